// Round 1
// baseline (192.858 us; speedup 1.0000x reference)
//
#include <hip/hip_runtime.h>
#include <math.h>

// Fixed problem geometry (from reference): T=8192, H=512, MC=MD=4096,
// N_ENT=128, MAX_DIST=600, feature dim 100. H and NFEAT are compile-time
// (LDS sizing); mention counts come from in_sizes; n_dis read on device.
#define H_DIM  512
#define NFEAT  100
#define MAXD   600
#define G_MENT 8     // mentions per block in mention_kernel
#define CPB    4     // chem mentions per block in pair_kernel
#define NDMAX  512   // max n_dis supported by the LDS-table fast path

#define NEG_ENC 0x007FFFFFu  // enc_f(-inf)

// Monotonic float->uint mapping so unsigned atomicMax == float max.
__device__ __forceinline__ unsigned enc_f(float f){
    unsigned u = __float_as_uint(f);
    return (u & 0x80000000u) ? ~u : (u | 0x80000000u);
}
__device__ __forceinline__ float dec_f(unsigned e){
    unsigned u = (e & 0x80000000u) ? (e ^ 0x80000000u) : ~e;
    return __uint_as_float(u);
}

// emb_sc[d,k] = sum_q Wemb[d,q] * Ws[200+q, k]   (600x50 @ 50x2)
__global__ void emb_kernel(const float* __restrict__ Wemb,
                           const float* __restrict__ Ws,
                           float* __restrict__ emb_sc){
    int d = blockIdx.x * blockDim.x + threadIdx.x;
    if (d < MAXD){
        float a0 = 0.f, a1 = 0.f;
        #pragma unroll 5
        for (int q = 0; q < 50; ++q){
            float w = Wemb[d*50 + q];
            a0 += w * Ws[(200+q)*2 + 0];
            a1 += w * Ws[(200+q)*2 + 1];
        }
        emb_sc[d*2 + 0] = a0;
        emb_sc[d*2 + 1] = a1;
    }
}

__global__ void init_kernel(unsigned* __restrict__ gent, int n){
    int i = blockIdx.x * blockDim.x + threadIdx.x;
    if (i < n) gent[i] = NEG_ENC;
}

// Per-mention: span-sum over h rows, dense 512->100 + tanh, contract with
// Ws rows -> sc[m, 2]. Handles chem blocks then dis blocks in one grid.
__global__ __launch_bounds__(128) void mention_kernel(
    const float* __restrict__ h,
    const int*   __restrict__ cspans, const int* __restrict__ dspans,
    const float* __restrict__ Wc, const float* __restrict__ bc,
    const float* __restrict__ Wd, const float* __restrict__ bd,
    const float* __restrict__ Ws,
    float* __restrict__ sc_c, float* __restrict__ sc_d,
    int MCv, int MDv, int nblk_c)
{
    __shared__ float sv[G_MENT][H_DIM];          // span-sum vectors
    __shared__ float fl[NFEAT][G_MENT*2 + 1];    // +1 pad: bank-conflict-free

    const int tid  = threadIdx.x;
    const bool isd = (blockIdx.x >= (unsigned)nblk_c);
    const int blk  = isd ? (blockIdx.x - nblk_c) : blockIdx.x;
    const int*   spans = isd ? dspans : cspans;
    const float* W     = isd ? Wd : Wc;
    const float* b     = isd ? bd : bc;
    float*       sc    = isd ? sc_d : sc_c;
    const int    M     = isd ? MDv : MCv;
    const int    wsoff = isd ? NFEAT : 0;
    const int    base  = blk * G_MENT;

    // 1) span sums into LDS (rows of h are 2KB, coalesced across the block)
    for (int g = 0; g < G_MENT; ++g){
        int m = base + g;
        int s = 0, e = -1;
        if (m < M){ s = spans[m*2]; e = spans[m*2 + 1]; }
        for (int t = tid; t < H_DIM; t += 128){
            float acc = 0.f;
            for (int r = s; r <= e; ++r) acc += h[r*H_DIM + t];
            sv[g][t] = acc;
        }
    }
    __syncthreads();

    // 2) 100 output features; thread j owns feature j for all G mentions.
    if (tid < NFEAT){
        float acc[G_MENT];
        const float bb = b[tid];
        #pragma unroll
        for (int g = 0; g < G_MENT; ++g) acc[g] = bb;
        #pragma unroll 4
        for (int t = 0; t < H_DIM; ++t){
            float w = W[t*NFEAT + tid];   // coalesced across j, L2-resident
            #pragma unroll
            for (int g = 0; g < G_MENT; ++g) acc[g] += sv[g][t] * w;  // LDS broadcast
        }
        const float w0 = Ws[(wsoff + tid)*2 + 0];
        const float w1 = Ws[(wsoff + tid)*2 + 1];
        #pragma unroll
        for (int g = 0; g < G_MENT; ++g){
            float f = tanhf(acc[g]);
            fl[tid][g*2 + 0] = f * w0;
            fl[tid][g*2 + 1] = f * w1;
        }
    }
    __syncthreads();

    // 3) reduce the 100 features -> sc[m, k]; 16 tiny serial sums.
    if (tid < G_MENT*2){
        int g = tid >> 1;
        int m = base + g;
        if (m < M){
            float s = 0.f;
            for (int j = 0; j < NFEAT; ++j) s += fl[j][tid];
            sc[m*2 + (tid & 1)] = s;
        }
    }
}

// All 16.7M mention pairs -> per-(chem_ent, dis_ent) running max.
// One block = CPB chem mentions x all dis mentions; LDS max table keyed by
// (local chem, dis_ent), flushed with global atomicMax at the end.
__global__ __launch_bounds__(256) void pair_kernel(
    const int*   __restrict__ cspans, const int* __restrict__ cent,
    const int*   __restrict__ dspans, const int* __restrict__ dent,
    const float* __restrict__ sc_c,   const float* __restrict__ sc_d,
    const float* __restrict__ emb_sc, const float* __restrict__ bs,
    const int*   __restrict__ ndp,    unsigned* __restrict__ gent,
    int MCv, int MDv)
{
    __shared__ float    s_e0[MAXD], s_e1[MAXD];
    __shared__ unsigned tab[CPB * NDMAX * 2];

    const int tid = threadIdx.x;
    const int nd  = *ndp;
    const bool use_lds = (nd <= NDMAX);

    for (int i = tid; i < MAXD; i += 256){
        s_e0[i] = emb_sc[i*2 + 0];
        s_e1[i] = emb_sc[i*2 + 1];
    }
    if (use_lds)
        for (int i = tid; i < CPB*nd*2; i += 256) tab[i] = NEG_ENC;

    const int cbase = blockIdx.x * CPB;
    int   cs[CPB], cet[CPB];
    float c0[CPB], c1[CPB];
    #pragma unroll
    for (int c = 0; c < CPB; ++c){
        int ci = cbase + c;
        if (ci < MCv){
            cs[c]  = cspans[ci*2];
            cet[c] = cent[ci];
            c0[c]  = sc_c[ci*2 + 0];
            c1[c]  = sc_c[ci*2 + 1];
        } else {
            cs[c] = 0; cet[c] = 0;
            c0[c] = __uint_as_float(0xFF800000u);  // -inf -> atomics no-op
            c1[c] = __uint_as_float(0xFF800000u);
        }
    }
    const float b0 = bs[0], b1 = bs[1];
    __syncthreads();

    const int2*   dsp2 = (const int2*)dspans;
    const float2* scd2 = (const float2*)sc_d;
    for (int j = tid; j < MDv; j += 256){
        int2   sp = dsp2[j];
        int    de = dent[j];
        float2 sd = scd2[j];
        #pragma unroll
        for (int c = 0; c < CPB; ++c){
            int dd = cs[c] - sp.x;
            dd = dd < 0 ? -dd : dd;
            dd = dd < (MAXD-1) ? dd : (MAXD-1);
            float s0 = c0[c] + sd.x + s_e0[dd] + b0;
            float s1 = c1[c] + sd.y + s_e1[dd] + b1;
            if (use_lds){
                atomicMax(&tab[(c*nd + de)*2 + 0], enc_f(s0));
                atomicMax(&tab[(c*nd + de)*2 + 1], enc_f(s1));
            } else {
                atomicMax(&gent[(cet[c]*nd + de)*2 + 0], enc_f(s0));
                atomicMax(&gent[(cet[c]*nd + de)*2 + 1], enc_f(s1));
            }
        }
    }
    if (use_lds){
        __syncthreads();
        for (int p = tid; p < CPB*nd*2; p += 256){
            int c = p / (nd*2);
            int rem = p - c*(nd*2);
            if (cbase + c < MCv)
                atomicMax(&gent[cet[c]*nd*2 + rem], tab[p]);
        }
    }
}

__global__ void softmax_kernel(const unsigned* __restrict__ gent,
                               float* __restrict__ out, int npairs){
    int p = blockIdx.x * blockDim.x + threadIdx.x;
    if (p < npairs){
        float a = dec_f(gent[p*2 + 0]);
        float b = dec_f(gent[p*2 + 1]);
        float m = fmaxf(a, b);
        float ea = expf(a - m), eb = expf(b - m);
        float inv = 1.f / (ea + eb);
        out[p*2 + 0] = ea * inv;
        out[p*2 + 1] = eb * inv;
    }
}

extern "C" void kernel_launch(void* const* d_in, const int* in_sizes, int n_in,
                              void* d_out, int out_size, void* d_ws, size_t ws_size,
                              hipStream_t stream)
{
    const float* h      = (const float*)d_in[0];
    const int*   cspans = (const int*)  d_in[1];
    const int*   centp  = (const int*)  d_in[2];
    const int*   dspans = (const int*)  d_in[3];
    const int*   dentp  = (const int*)  d_in[4];
    const float* Wc     = (const float*)d_in[5];
    const float* bc     = (const float*)d_in[6];
    const float* Wd     = (const float*)d_in[7];
    const float* bd     = (const float*)d_in[8];
    const float* Wemb   = (const float*)d_in[9];
    const float* Ws     = (const float*)d_in[10];
    const float* bs     = (const float*)d_in[11];
    const int*   ndp    = (const int*)  d_in[13];

    const int MCv    = in_sizes[1] / 2;
    const int MDv    = in_sizes[3] / 2;
    const int npairs = out_size / 2;

    // Workspace layout (floats/u32): emb_sc[1280 pad] | sc_c[2*MC] | sc_d[2*MD] | gent[out_size]
    float*    wsf    = (float*)d_ws;
    float*    emb_sc = wsf;
    float*    sc_c   = wsf + 1280;
    float*    sc_d   = sc_c + (size_t)MCv * 2;
    unsigned* gent   = (unsigned*)(sc_d + (size_t)MDv * 2);

    hipLaunchKernelGGL(emb_kernel, dim3((MAXD + 255)/256), dim3(256), 0, stream,
                       Wemb, Ws, emb_sc);
    hipLaunchKernelGGL(init_kernel, dim3((out_size + 255)/256), dim3(256), 0, stream,
                       gent, out_size);

    const int nblk_c = (MCv + G_MENT - 1) / G_MENT;
    const int nblk_d = (MDv + G_MENT - 1) / G_MENT;
    hipLaunchKernelGGL(mention_kernel, dim3(nblk_c + nblk_d), dim3(128), 0, stream,
                       h, cspans, dspans, Wc, bc, Wd, bd, Ws, sc_c, sc_d,
                       MCv, MDv, nblk_c);

    hipLaunchKernelGGL(pair_kernel, dim3((MCv + CPB - 1)/CPB), dim3(256), 0, stream,
                       cspans, centp, dspans, dentp, sc_c, sc_d, emb_sc, bs,
                       ndp, gent, MCv, MDv);

    hipLaunchKernelGGL(softmax_kernel, dim3((npairs + 255)/256), dim3(256), 0, stream,
                       gent, (float*)d_out, npairs);
}

// Round 2
// 185.956 us; speedup vs baseline: 1.0371x; 1.0371x over previous
//
#include <hip/hip_runtime.h>
#include <math.h>
#include <limits.h>

// Fixed geometry from reference: T=8192, H=512, MC=MD=4096, N_ENT=128,
// MAX_DIST=600, feature dim 100. Mention counts from in_sizes; n_chem/n_dis
// are device scalars (read on device only).
#define H_DIM  512
#define NFEAT  100
#define MAXD   600
#define G_MENT 8      // mentions per block in mention_kernel
#define MAXE   2048   // sort fast-path entity-count limit
#define CHK    128    // dis mentions per staged chunk in pair kernel
#define DCH    32     // grid.y = number of dis-chunk streams

#define NEG_ENC 0x007FFFFFu  // enc_f(-inf)

// Monotonic float->uint mapping so unsigned atomicMax == float max.
__device__ __forceinline__ unsigned enc_f(float f){
    unsigned u = __float_as_uint(f);
    return (u & 0x80000000u) ? ~u : (u | 0x80000000u);
}
__device__ __forceinline__ float dec_f(unsigned e){
    unsigned u = (e & 0x80000000u) ? (e ^ 0x80000000u) : ~e;
    return __uint_as_float(u);
}

// emb2[d] = Wemb[d,:] @ Ws[200:250, :] + bs   (bias folded in)
__global__ void emb_kernel(const float* __restrict__ Wemb,
                           const float* __restrict__ Ws,
                           const float* __restrict__ bs,
                           float* __restrict__ emb2){
    int d = blockIdx.x * blockDim.x + threadIdx.x;
    if (d < MAXD){
        float a0 = bs[0], a1 = bs[1];
        #pragma unroll 5
        for (int q = 0; q < 50; ++q){
            float w = Wemb[d*50 + q];
            a0 += w * Ws[(200+q)*2 + 0];
            a1 += w * Ws[(200+q)*2 + 1];
        }
        emb2[d*2 + 0] = a0;
        emb2[d*2 + 1] = a1;
    }
}

__global__ void init_kernel(unsigned* __restrict__ gent, int n){
    int i = blockIdx.x * blockDim.x + threadIdx.x;
    if (i < n) gent[i] = NEG_ENC;
}

// One-block bucket sort of mentions by entity id (chem then dis).
// Output record: int4{span_start, ent, orig_idx, 0}. If ne > MAXE, fall back
// to identity order (pair kernel stays correct, just does more atomics).
__global__ __launch_bounds__(256) void sort_kernel(
    const int* __restrict__ cent, const int* __restrict__ dent,
    const int* __restrict__ ncp,  const int* __restrict__ ndp,
    const int* __restrict__ cspans, const int* __restrict__ dspans,
    int4* __restrict__ csorted, int4* __restrict__ dsorted,
    int MCv, int MDv)
{
    __shared__ int cnt[MAXE];
    __shared__ int tmp[MAXE];
    const int tid = threadIdx.x;

    for (int side = 0; side < 2; ++side){
        const int* ent   = side ? dent   : cent;
        const int* spans = side ? dspans : cspans;
        int4*      out   = side ? dsorted : csorted;
        const int  M     = side ? MDv : MCv;
        const int  ne    = side ? *ndp : *ncp;
        __syncthreads();
        if (ne <= MAXE){
            for (int i = tid; i < ne; i += 256) cnt[i] = 0;
            __syncthreads();
            for (int i = tid; i < M; i += 256) atomicAdd(&cnt[ent[i]], 1);
            __syncthreads();
            // inclusive scan (Hillis-Steele, ping-pong)
            int* src = cnt; int* dst = tmp;
            for (int off = 1; off < ne; off <<= 1){
                for (int i = tid; i < ne; i += 256)
                    dst[i] = src[i] + ((i >= off) ? src[i - off] : 0);
                __syncthreads();
                int* t_ = src; src = dst; dst = t_;
            }
            // exclusive starts into dst
            for (int i = tid; i < ne; i += 256) dst[i] = i ? src[i-1] : 0;
            __syncthreads();
            for (int i = tid; i < M; i += 256){
                int e = ent[i];
                int pos = atomicAdd(&dst[e], 1);
                out[pos] = make_int4(spans[i*2], e, i, 0);
            }
        } else {
            for (int i = tid; i < M; i += 256)
                out[i] = make_int4(spans[i*2], ent[i], i, 0);
        }
        __syncthreads();
    }
}

// Per-mention: span-sum (8 predicated pipelined row loads), dense 512->100
// + tanh, contract with Ws -> sc[m,2]. Chem blocks then dis blocks.
__global__ __launch_bounds__(128) void mention_kernel(
    const float* __restrict__ h,
    const int*   __restrict__ cspans, const int* __restrict__ dspans,
    const float* __restrict__ Wc, const float* __restrict__ bc,
    const float* __restrict__ Wd, const float* __restrict__ bd,
    const float* __restrict__ Ws,
    float* __restrict__ sc_c, float* __restrict__ sc_d,
    int MCv, int MDv, int nblk_c)
{
    __shared__ float sv[G_MENT][H_DIM];
    __shared__ float fl[NFEAT][G_MENT*2 + 1];

    const int tid  = threadIdx.x;
    const bool isd = (blockIdx.x >= (unsigned)nblk_c);
    const int blk  = isd ? (blockIdx.x - nblk_c) : blockIdx.x;
    const int*   spans = isd ? dspans : cspans;
    const float* W     = isd ? Wd : Wc;
    const float* b     = isd ? bd : bc;
    float*       sc    = isd ? sc_d : sc_c;
    const int    M     = isd ? MDv : MCv;
    const int    wsoff = isd ? NFEAT : 0;
    const int    base  = blk * G_MENT;

    // 1) span sums: rows/mention <= 8 always -> 8 independent predicated loads
    #pragma unroll
    for (int g = 0; g < G_MENT; ++g){
        int m = base + g;
        int s = 0, len = -1;
        if (m < M){ s = spans[m*2]; len = spans[m*2 + 1] - s; }  // 0..7
        #pragma unroll
        for (int tt = 0; tt < H_DIM/128; ++tt){
            int t = tid + tt*128;
            const float* hp = h + (size_t)s * H_DIM + t;
            float v[8];
            #pragma unroll
            for (int r = 0; r < 8; ++r) v[r] = hp[(size_t)r * H_DIM];
            float acc = 0.f;
            #pragma unroll
            for (int r = 0; r < 8; ++r) acc += (r <= len) ? v[r] : 0.f;
            sv[g][t] = acc;
        }
    }
    __syncthreads();

    // 2) features: all 128 lanes compute (lanes >=100 duplicate f99, unstored).
    {
        const int jj = (tid < NFEAT) ? tid : (NFEAT - 1);
        float acc[G_MENT];
        const float bb = b[jj];
        #pragma unroll
        for (int g = 0; g < G_MENT; ++g) acc[g] = bb;
        for (int t4 = 0; t4 < H_DIM/4; ++t4){
            const int t = t4 * 4;
            float w0 = W[(t+0)*NFEAT + jj];
            float w1 = W[(t+1)*NFEAT + jj];
            float w2 = W[(t+2)*NFEAT + jj];
            float w3 = W[(t+3)*NFEAT + jj];
            #pragma unroll
            for (int g = 0; g < G_MENT; ++g){
                float4 s4 = *reinterpret_cast<const float4*>(&sv[g][t]); // broadcast b128
                acc[g] += s4.x*w0 + s4.y*w1 + s4.z*w2 + s4.w*w3;
            }
        }
        if (tid < NFEAT){
            const float w0 = Ws[(wsoff + tid)*2 + 0];
            const float w1 = Ws[(wsoff + tid)*2 + 1];
            #pragma unroll
            for (int g = 0; g < G_MENT; ++g){
                float f = tanhf(acc[g]);
                fl[tid][g*2 + 0] = f * w0;
                fl[tid][g*2 + 1] = f * w1;
            }
        }
    }
    __syncthreads();

    // 3) reduce 100 features -> sc[m,k]
    if (tid < G_MENT*2){
        int g = tid >> 1;
        int m = base + g;
        if (m < M){
            float s = 0.f;
            for (int j = 0; j < NFEAT; ++j) s += fl[j][tid];
            sc[m*2 + (tid & 1)] = s;
        }
    }
}

// Segmented (by ce, contiguous after sort) suffix max-reduce + head atomics.
__device__ __forceinline__ void flush_run(
    float s0, float s1, int ce, int de, int nd, bool head,
    const bool okk[6], unsigned* __restrict__ gent)
{
    float a0 = s0, a1 = s1;
    #pragma unroll
    for (int k = 0; k < 6; ++k){
        float b0 = __shfl_down(a0, 1 << k);
        float b1 = __shfl_down(a1, 1 << k);
        if (okk[k]){ a0 = fmaxf(a0, b0); a1 = fmaxf(a1, b1); }
    }
    if (head && ce != INT_MAX){
        atomicMax(&gent[(ce*nd + de)*2 + 0], enc_f(a0));
        atomicMax(&gent[(ce*nd + de)*2 + 1], enc_f(a1));
    }
}

// 256 sorted chem mentions per block (one per lane); stream sorted dis
// mentions in staged chunks; per-lane running max per dis-entity run;
// boundary flush via wave-segmented reduce -> few global atomics.
__global__ __launch_bounds__(256) void pair_kernel(
    const int4* __restrict__ csorted, const int4* __restrict__ dsorted,
    const float* __restrict__ sc_c,   const float* __restrict__ sc_d,
    const float* __restrict__ emb2,   const int* __restrict__ ndp,
    unsigned* __restrict__ gent, int MCv, int MDv)
{
    __shared__ float2 s_e[MAXD];
    __shared__ int4   s_d[CHK];

    const int tid  = threadIdx.x;
    const int lane = tid & 63;
    const int nd   = *ndp;

    const float2* e2 = (const float2*)emb2;
    for (int i = tid; i < MAXD; i += 256) s_e[i] = e2[i];

    int   cs = 0, ce = INT_MAX;
    float c0 = 0.f, c1 = 0.f;
    {
        int ci = blockIdx.x * 256 + tid;
        if (ci < MCv){
            int4 r = csorted[ci];
            cs = r.x; ce = r.y;
            const float2 sc = *reinterpret_cast<const float2*>(&sc_c[2*r.z]);
            c0 = sc.x; c1 = sc.y;
        }
    }
    int ceprev = __shfl_up(ce, 1);
    const bool head = (lane == 0) || (ceprev != ce);
    bool okk[6];
    #pragma unroll
    for (int k = 0; k < 6; ++k) okk[k] = (__shfl_down(ce, 1 << k) == ce);

    for (int cb = blockIdx.y; cb * CHK < MDv; cb += DCH){
        const int dbase = cb * CHK;
        const int n = min(CHK, MDv - dbase);
        __syncthreads();   // protect s_d from previous chunk's readers
        for (int i = tid; i < n; i += 256){
            int4 r = dsorted[dbase + i];
            const float2 sd = *reinterpret_cast<const float2*>(&sc_d[2*r.z]);
            s_d[i] = make_int4(r.x, r.y, __float_as_int(sd.x), __float_as_int(sd.y));
        }
        __syncthreads();

        int   cur_de = s_d[0].y;
        float s0 = -INFINITY, s1 = -INFINITY;
        for (int j = 0; j < n; ++j){
            int4 dj = s_d[j];                 // broadcast b128
            if (dj.y != cur_de){              // uniform branch
                flush_run(s0, s1, ce, cur_de, nd, head, okk, gent);
                cur_de = dj.y; s0 = -INFINITY; s1 = -INFINITY;
            }
            int dd = cs - dj.x; dd = dd < 0 ? -dd : dd;
            dd = dd < (MAXD-1) ? dd : (MAXD-1);
            float2 e = s_e[dd];               // gather b64
            s0 = fmaxf(s0, c0 + __int_as_float(dj.z) + e.x);
            s1 = fmaxf(s1, c1 + __int_as_float(dj.w) + e.y);
        }
        flush_run(s0, s1, ce, cur_de, nd, head, okk, gent);
    }
}

__global__ void softmax_kernel(const unsigned* __restrict__ gent,
                               float* __restrict__ out, int npairs){
    int p = blockIdx.x * blockDim.x + threadIdx.x;
    if (p < npairs){
        float a = dec_f(gent[p*2 + 0]);
        float b = dec_f(gent[p*2 + 1]);
        float m = fmaxf(a, b);
        float ea = expf(a - m), eb = expf(b - m);
        float inv = 1.f / (ea + eb);
        out[p*2 + 0] = ea * inv;
        out[p*2 + 1] = eb * inv;
    }
}

extern "C" void kernel_launch(void* const* d_in, const int* in_sizes, int n_in,
                              void* d_out, int out_size, void* d_ws, size_t ws_size,
                              hipStream_t stream)
{
    const float* h      = (const float*)d_in[0];
    const int*   cspans = (const int*)  d_in[1];
    const int*   centp  = (const int*)  d_in[2];
    const int*   dspans = (const int*)  d_in[3];
    const int*   dentp  = (const int*)  d_in[4];
    const float* Wc     = (const float*)d_in[5];
    const float* bc     = (const float*)d_in[6];
    const float* Wd     = (const float*)d_in[7];
    const float* bd     = (const float*)d_in[8];
    const float* Wemb   = (const float*)d_in[9];
    const float* Ws     = (const float*)d_in[10];
    const float* bs     = (const float*)d_in[11];
    const int*   ncp    = (const int*)  d_in[12];
    const int*   ndp    = (const int*)  d_in[13];

    const int MCv    = in_sizes[1] / 2;
    const int MDv    = in_sizes[3] / 2;
    const int npairs = out_size / 2;

    // ws layout (4B units): emb2[1280] | sc_c[2MC] | sc_d[2MD] | gent[out_size]
    //                      | csorted[4MC] | dsorted[4MD]   (int4-aligned)
    float*    wsf    = (float*)d_ws;
    float*    emb2   = wsf;
    float*    sc_c   = wsf + 1280;
    float*    sc_d   = sc_c + (size_t)MCv * 2;
    unsigned* gent   = (unsigned*)(sc_d + (size_t)MDv * 2);
    int4*     csorted= (int4*)(gent + out_size);
    int4*     dsorted= csorted + MCv;

    hipLaunchKernelGGL(emb_kernel, dim3((MAXD + 255)/256), dim3(256), 0, stream,
                       Wemb, Ws, bs, emb2);
    hipLaunchKernelGGL(init_kernel, dim3((out_size + 255)/256), dim3(256), 0, stream,
                       gent, out_size);
    hipLaunchKernelGGL(sort_kernel, dim3(1), dim3(256), 0, stream,
                       centp, dentp, ncp, ndp, cspans, dspans,
                       csorted, dsorted, MCv, MDv);

    const int nblk_c = (MCv + G_MENT - 1) / G_MENT;
    const int nblk_d = (MDv + G_MENT - 1) / G_MENT;
    hipLaunchKernelGGL(mention_kernel, dim3(nblk_c + nblk_d), dim3(128), 0, stream,
                       h, cspans, dspans, Wc, bc, Wd, bd, Ws, sc_c, sc_d,
                       MCv, MDv, nblk_c);

    hipLaunchKernelGGL(pair_kernel, dim3((MCv + 255)/256, DCH), dim3(256), 0, stream,
                       csorted, dsorted, sc_c, sc_d, emb2, ndp, gent, MCv, MDv);

    hipLaunchKernelGGL(softmax_kernel, dim3((npairs + 255)/256), dim3(256), 0, stream,
                       gent, (float*)d_out, npairs);
}

// Round 3
// 165.882 us; speedup vs baseline: 1.1626x; 1.1210x over previous
//
#include <hip/hip_runtime.h>
#include <math.h>
#include <limits.h>

// Fixed geometry from reference: T=8192, H=512, MC=MD=4096, N_ENT=128,
// MAX_DIST=600, feature dim 100. Mention counts from in_sizes; n_chem/n_dis
// are device scalars (read on device only).
#define H_DIM  512
#define NFEAT  100
#define MAXD   600
#define G_MENT 8      // mentions per block in mention_kernel
#define MAXE   2048   // sort fast-path entity-count limit
#define CHK    64     // dis mentions per staged chunk in pair kernel
#define DCH    64     // grid.y = number of dis-chunk streams

#define NEG_ENC 0x007FFFFFu  // enc_f(-inf)

// Monotonic float->uint mapping so unsigned atomicMax == float max.
__device__ __forceinline__ unsigned enc_f(float f){
    unsigned u = __float_as_uint(f);
    return (u & 0x80000000u) ? ~u : (u | 0x80000000u);
}
__device__ __forceinline__ float dec_f(unsigned e){
    unsigned u = (e & 0x80000000u) ? (e ^ 0x80000000u) : ~e;
    return __uint_as_float(u);
}

// Fused prep: block 0 = bucket-sort mentions by entity; blocks [1, 1+gb) =
// init gent to -inf; blocks [1+gb, ...) = emb2[d] = Wemb[d,:]@Ws[200:250]+bs.
__global__ __launch_bounds__(256) void prep_kernel(
    const float* __restrict__ Wemb, const float* __restrict__ Ws,
    const float* __restrict__ bs,
    const int* __restrict__ cent, const int* __restrict__ dent,
    const int* __restrict__ ncp,  const int* __restrict__ ndp,
    const int* __restrict__ cspans, const int* __restrict__ dspans,
    float* __restrict__ emb2, unsigned* __restrict__ gent, int gent_n, int gb,
    int4* __restrict__ csorted, int4* __restrict__ dsorted,
    int MCv, int MDv)
{
    const int tid = threadIdx.x;
    const int bid = blockIdx.x;

    if (bid == 0){
        __shared__ int cnt[MAXE];
        __shared__ int tmp[MAXE];
        for (int side = 0; side < 2; ++side){
            const int* ent   = side ? dent   : cent;
            const int* spans = side ? dspans : cspans;
            int4*      out   = side ? dsorted : csorted;
            const int  M     = side ? MDv : MCv;
            const int  ne    = side ? *ndp : *ncp;
            __syncthreads();
            if (ne <= MAXE){
                for (int i = tid; i < ne; i += 256) cnt[i] = 0;
                __syncthreads();
                for (int i = tid; i < M; i += 256) atomicAdd(&cnt[ent[i]], 1);
                __syncthreads();
                int* src = cnt; int* dst = tmp;
                for (int off = 1; off < ne; off <<= 1){
                    for (int i = tid; i < ne; i += 256)
                        dst[i] = src[i] + ((i >= off) ? src[i - off] : 0);
                    __syncthreads();
                    int* t_ = src; src = dst; dst = t_;
                }
                for (int i = tid; i < ne; i += 256) dst[i] = i ? src[i-1] : 0;
                __syncthreads();
                for (int i = tid; i < M; i += 256){
                    int e = ent[i];
                    int pos = atomicAdd(&dst[e], 1);
                    out[pos] = make_int4(spans[i*2], e, i, 0);
                }
            } else {
                for (int i = tid; i < M; i += 256)
                    out[i] = make_int4(spans[i*2], ent[i], i, 0);
            }
            __syncthreads();
        }
    } else if (bid <= gb){
        int i = (bid - 1) * 256 + tid;
        if (i < gent_n) gent[i] = NEG_ENC;
    } else {
        int d = (bid - 1 - gb) * 256 + tid;
        if (d < MAXD){
            float a0 = bs[0], a1 = bs[1];
            #pragma unroll 5
            for (int q = 0; q < 50; ++q){
                float w = Wemb[d*50 + q];
                a0 += w * Ws[(200+q)*2 + 0];
                a1 += w * Ws[(200+q)*2 + 1];
            }
            emb2[d*2 + 0] = a0;
            emb2[d*2 + 1] = a1;
        }
    }
}

// Per-mention: span-sum, dense 512->100 + tanh, contract with Ws -> sc[m,2].
// 256 threads = 2 K-halves x 128 feature lanes; partials combined in LDS.
__global__ __launch_bounds__(256) void mention_kernel(
    const float* __restrict__ h,
    const int*   __restrict__ cspans, const int* __restrict__ dspans,
    const float* __restrict__ Wc, const float* __restrict__ bc,
    const float* __restrict__ Wd, const float* __restrict__ bd,
    const float* __restrict__ Ws,
    float* __restrict__ sc_c, float* __restrict__ sc_d,
    int MCv, int MDv, int nblk_c)
{
    __shared__ float sv[G_MENT][H_DIM];
    __shared__ float part[2][NFEAT][G_MENT + 1];   // stride 9: conflict-free
    __shared__ float fl[NFEAT][G_MENT*2 + 1];
    __shared__ float red[G_MENT*2][9];

    const int tid  = threadIdx.x;
    const bool isd = (blockIdx.x >= (unsigned)nblk_c);
    const int blk  = isd ? (blockIdx.x - nblk_c) : blockIdx.x;
    const int*   spans = isd ? dspans : cspans;
    const float* W     = isd ? Wd : Wc;
    const float* b     = isd ? bd : bc;
    float*       sc    = isd ? sc_d : sc_c;
    const int    M     = isd ? MDv : MCv;
    const int    wsoff = isd ? NFEAT : 0;
    const int    base  = blk * G_MENT;

    // 1) span sums: rows/mention <= 8 -> 8 independent predicated loads.
    #pragma unroll
    for (int g = 0; g < G_MENT; ++g){
        int m = base + g;
        int s = 0, len = -1;
        if (m < M){ s = spans[m*2]; len = spans[m*2 + 1] - s; }  // len 0..7
        #pragma unroll
        for (int tt = 0; tt < H_DIM/256; ++tt){
            int t = tid + tt*256;
            const float* hp = h + (size_t)s * H_DIM + t;
            float v[8];
            #pragma unroll
            for (int r = 0; r < 8; ++r) v[r] = hp[(size_t)r * H_DIM];
            float acc = 0.f;
            #pragma unroll
            for (int r = 0; r < 8; ++r) acc += (r <= len) ? v[r] : 0.f;
            sv[g][t] = acc;
        }
    }
    __syncthreads();

    // 2) features, split-K: half = tid>>7 covers 256 of 512 positions.
    {
        const int j    = tid & 127;
        const int jj   = (j < NFEAT) ? j : (NFEAT - 1);
        const int half = tid >> 7;
        float acc[G_MENT];
        #pragma unroll
        for (int g = 0; g < G_MENT; ++g) acc[g] = 0.f;
        const int t0 = half * (H_DIM/2);
        for (int t4 = 0; t4 < H_DIM/8; ++t4){   // 64 iters x 4 positions
            const int t = t0 + t4*4;
            float w0 = W[(t+0)*NFEAT + jj];
            float w1 = W[(t+1)*NFEAT + jj];
            float w2 = W[(t+2)*NFEAT + jj];
            float w3 = W[(t+3)*NFEAT + jj];
            #pragma unroll
            for (int g = 0; g < G_MENT; ++g){
                float4 s4 = *reinterpret_cast<const float4*>(&sv[g][t]); // broadcast
                acc[g] += s4.x*w0 + s4.y*w1 + s4.z*w2 + s4.w*w3;
            }
        }
        if (j < NFEAT){
            #pragma unroll
            for (int g = 0; g < G_MENT; ++g) part[half][j][g] = acc[g];
        }
    }
    __syncthreads();

    // combine halves, tanh, fold Ws
    if (tid < NFEAT){
        const float bb = b[tid];
        const float w0 = Ws[(wsoff + tid)*2 + 0];
        const float w1 = Ws[(wsoff + tid)*2 + 1];
        #pragma unroll
        for (int g = 0; g < G_MENT; ++g){
            float f = tanhf(part[0][tid][g] + part[1][tid][g] + bb);
            fl[tid][g*2 + 0] = f * w0;
            fl[tid][g*2 + 1] = f * w1;
        }
    }
    __syncthreads();

    // 3) two-level reduce of 100 features -> sc[m,k]
    if (tid < 128){
        int col = tid >> 3, sub = tid & 7;
        int j0 = sub * 13, j1 = (j0 + 13 < NFEAT) ? (j0 + 13) : NFEAT;
        float s = 0.f;
        for (int j = j0; j < j1; ++j) s += fl[j][col];
        red[col][sub] = s;
    }
    __syncthreads();
    if (tid < G_MENT*2){
        float s = 0.f;
        #pragma unroll
        for (int k = 0; k < 8; ++k) s += red[tid][k];
        int g = tid >> 1;
        int m = base + g;
        if (m < M) sc[m*2 + (tid & 1)] = s;
    }
}

// Segmented (by ce, contiguous after sort) suffix max-reduce + head atomics.
__device__ __forceinline__ void flush_run(
    float s0, float s1, int ce, int de, int nd, bool head,
    const bool okk[6], unsigned* __restrict__ gent)
{
    float a0 = s0, a1 = s1;
    #pragma unroll
    for (int k = 0; k < 6; ++k){
        float b0 = __shfl_down(a0, 1 << k);
        float b1 = __shfl_down(a1, 1 << k);
        if (okk[k]){ a0 = fmaxf(a0, b0); a1 = fmaxf(a1, b1); }
    }
    if (head && ce != INT_MAX){
        atomicMax(&gent[(ce*nd + de)*2 + 0], enc_f(a0));
        atomicMax(&gent[(ce*nd + de)*2 + 1], enc_f(a1));
    }
}

// 256 sorted chem mentions per block (one per lane); stream sorted dis
// mentions in staged chunks; per-lane running max per dis-entity run;
// boundary flush via wave-segmented reduce -> few global atomics.
__global__ __launch_bounds__(256) void pair_kernel(
    const int4* __restrict__ csorted, const int4* __restrict__ dsorted,
    const float* __restrict__ sc_c,   const float* __restrict__ sc_d,
    const float* __restrict__ emb2,   const int* __restrict__ ndp,
    unsigned* __restrict__ gent, int MCv, int MDv)
{
    __shared__ float2 s_e[MAXD];
    __shared__ int4   s_d[CHK];

    const int tid  = threadIdx.x;
    const int lane = tid & 63;
    const int nd   = *ndp;

    const float2* e2 = (const float2*)emb2;
    for (int i = tid; i < MAXD; i += 256) s_e[i] = e2[i];

    int   cs = 0, ce = INT_MAX;
    float c0 = 0.f, c1 = 0.f;
    {
        int ci = blockIdx.x * 256 + tid;
        if (ci < MCv){
            int4 r = csorted[ci];
            cs = r.x; ce = r.y;
            const float2 sc = *reinterpret_cast<const float2*>(&sc_c[2*r.z]);
            c0 = sc.x; c1 = sc.y;
        }
    }
    int ceprev = __shfl_up(ce, 1);
    const bool head = (lane == 0) || (ceprev != ce);
    bool okk[6];
    #pragma unroll
    for (int k = 0; k < 6; ++k) okk[k] = (__shfl_down(ce, 1 << k) == ce);

    for (int cb = blockIdx.y; cb * CHK < MDv; cb += DCH){
        const int dbase = cb * CHK;
        const int n = min(CHK, MDv - dbase);
        __syncthreads();   // protect s_d from previous chunk's readers
        for (int i = tid; i < n; i += 256){
            int4 r = dsorted[dbase + i];
            const float2 sd = *reinterpret_cast<const float2*>(&sc_d[2*r.z]);
            s_d[i] = make_int4(r.x, r.y, __float_as_int(sd.x), __float_as_int(sd.y));
        }
        __syncthreads();

        int   cur_de = s_d[0].y;
        float s0 = -INFINITY, s1 = -INFINITY;
        for (int j = 0; j < n; ++j){
            int4 dj = s_d[j];                 // broadcast b128
            if (dj.y != cur_de){              // uniform branch
                flush_run(s0, s1, ce, cur_de, nd, head, okk, gent);
                cur_de = dj.y; s0 = -INFINITY; s1 = -INFINITY;
            }
            int dd = cs - dj.x; dd = dd < 0 ? -dd : dd;
            dd = dd < (MAXD-1) ? dd : (MAXD-1);
            float2 e = s_e[dd];               // gather b64
            s0 = fmaxf(s0, c0 + __int_as_float(dj.z) + e.x);
            s1 = fmaxf(s1, c1 + __int_as_float(dj.w) + e.y);
        }
        flush_run(s0, s1, ce, cur_de, nd, head, okk, gent);
    }
}

__global__ void softmax_kernel(const unsigned* __restrict__ gent,
                               float* __restrict__ out, int npairs){
    int p = blockIdx.x * blockDim.x + threadIdx.x;
    if (p < npairs){
        float a = dec_f(gent[p*2 + 0]);
        float b = dec_f(gent[p*2 + 1]);
        float m = fmaxf(a, b);
        float ea = expf(a - m), eb = expf(b - m);
        float inv = 1.f / (ea + eb);
        out[p*2 + 0] = ea * inv;
        out[p*2 + 1] = eb * inv;
    }
}

extern "C" void kernel_launch(void* const* d_in, const int* in_sizes, int n_in,
                              void* d_out, int out_size, void* d_ws, size_t ws_size,
                              hipStream_t stream)
{
    const float* h      = (const float*)d_in[0];
    const int*   cspans = (const int*)  d_in[1];
    const int*   centp  = (const int*)  d_in[2];
    const int*   dspans = (const int*)  d_in[3];
    const int*   dentp  = (const int*)  d_in[4];
    const float* Wc     = (const float*)d_in[5];
    const float* bc     = (const float*)d_in[6];
    const float* Wd     = (const float*)d_in[7];
    const float* bd     = (const float*)d_in[8];
    const float* Wemb   = (const float*)d_in[9];
    const float* Ws     = (const float*)d_in[10];
    const float* bs     = (const float*)d_in[11];
    const int*   ncp    = (const int*)  d_in[12];
    const int*   ndp    = (const int*)  d_in[13];

    const int MCv    = in_sizes[1] / 2;
    const int MDv    = in_sizes[3] / 2;
    const int npairs = out_size / 2;

    // ws layout (4B units): emb2[1280] | sc_c[2MC] | sc_d[2MD] | gent[out_size]
    //                      | csorted[4MC] | dsorted[4MD]
    float*    wsf    = (float*)d_ws;
    float*    emb2   = wsf;
    float*    sc_c   = wsf + 1280;
    float*    sc_d   = sc_c + (size_t)MCv * 2;
    unsigned* gent   = (unsigned*)(sc_d + (size_t)MDv * 2);
    int4*     csorted= (int4*)(gent + out_size);
    int4*     dsorted= csorted + MCv;

    const int gb = (out_size + 255) / 256;           // init blocks
    const int eb = (MAXD + 255) / 256;               // emb blocks
    hipLaunchKernelGGL(prep_kernel, dim3(1 + gb + eb), dim3(256), 0, stream,
                       Wemb, Ws, bs, centp, dentp, ncp, ndp, cspans, dspans,
                       emb2, gent, out_size, gb, csorted, dsorted, MCv, MDv);

    const int nblk_c = (MCv + G_MENT - 1) / G_MENT;
    const int nblk_d = (MDv + G_MENT - 1) / G_MENT;
    hipLaunchKernelGGL(mention_kernel, dim3(nblk_c + nblk_d), dim3(256), 0, stream,
                       h, cspans, dspans, Wc, bc, Wd, bd, Ws, sc_c, sc_d,
                       MCv, MDv, nblk_c);

    hipLaunchKernelGGL(pair_kernel, dim3((MCv + 255)/256, DCH), dim3(256), 0, stream,
                       csorted, dsorted, sc_c, sc_d, emb2, ndp, gent, MCv, MDv);

    hipLaunchKernelGGL(softmax_kernel, dim3((npairs + 255)/256), dim3(256), 0, stream,
                       gent, (float*)d_out, npairs);
}

// Round 4
// 155.317 us; speedup vs baseline: 1.2417x; 1.0680x over previous
//
#include <hip/hip_runtime.h>
#include <math.h>
#include <limits.h>

// Fixed geometry from reference: T=8192, H=512, MC=MD=4096, N_ENT=128,
// MAX_DIST=600, feature dim 100 (padded to 112 for MFMA n-tiles).
#define H_DIM  512
#define NFEAT  100
#define NPAD   112
#define NT     7      // NPAD/16 n-tiles
#define MAXD   600
#define MAXE   2048   // sort fast-path entity-count limit
#define CHK    64     // dis mentions per staged chunk in pair kernel
#define DCH    64     // grid.y = number of dis-chunk streams

#define NEG_ENC 0x007FFFFFu  // enc_f(-inf)

typedef __attribute__((ext_vector_type(8))) short short8v;  // 8 bf16
typedef __attribute__((ext_vector_type(4))) float f32x4;

// Monotonic float->uint mapping so unsigned atomicMax == float max.
__device__ __forceinline__ unsigned enc_f(float f){
    unsigned u = __float_as_uint(f);
    return (u & 0x80000000u) ? ~u : (u | 0x80000000u);
}
__device__ __forceinline__ float dec_f(unsigned e){
    unsigned u = (e & 0x80000000u) ? (e ^ 0x80000000u) : ~e;
    return __uint_as_float(u);
}
__device__ __forceinline__ unsigned short f2bf(float f){  // round-nearest-even
    unsigned x = __float_as_uint(f);
    return (unsigned short)((x + 0x7fffu + ((x >> 16) & 1u)) >> 16);
}

// Fused prep, block roles by blockIdx.x:
//  [0]                : bucket-sort mentions by entity (1 block)
//  [1, off_e)         : gent init to -inf
//  [off_e, off_w)     : emb2[d] = Wemb[d,:]@Ws[200:250] + bs
//  [off_w, off_h)     : Wt[side][n][k] = bf16(W_side[k][n])  (zero-pad n>=100)
//  [off_h, ...)       : hbf = bf16(h)
__global__ __launch_bounds__(256) void prep_kernel(
    const float* __restrict__ h,
    const float* __restrict__ Wemb, const float* __restrict__ Ws,
    const float* __restrict__ bs,
    const float* __restrict__ Wc,   const float* __restrict__ Wd,
    const int* __restrict__ cent, const int* __restrict__ dent,
    const int* __restrict__ ncp,  const int* __restrict__ ndp,
    const int* __restrict__ cspans, const int* __restrict__ dspans,
    float* __restrict__ emb2, unsigned* __restrict__ gent, int gent_n,
    unsigned short* __restrict__ Wt, unsigned short* __restrict__ hbf,
    int4* __restrict__ csorted, int4* __restrict__ dsorted,
    int MCv, int MDv, int TT, int off_e, int off_w, int off_h)
{
    const int tid = threadIdx.x;
    const int bid = blockIdx.x;

    if (bid == 0){
        __shared__ int cnt[MAXE];
        __shared__ int tmp[MAXE];
        for (int side = 0; side < 2; ++side){
            const int* ent   = side ? dent   : cent;
            const int* spans = side ? dspans : cspans;
            int4*      out   = side ? dsorted : csorted;
            const int  M     = side ? MDv : MCv;
            const int  ne    = side ? *ndp : *ncp;
            __syncthreads();
            if (ne <= MAXE){
                for (int i = tid; i < ne; i += 256) cnt[i] = 0;
                __syncthreads();
                for (int i = tid; i < M; i += 256) atomicAdd(&cnt[ent[i]], 1);
                __syncthreads();
                int* src = cnt; int* dst = tmp;
                for (int off = 1; off < ne; off <<= 1){
                    for (int i = tid; i < ne; i += 256)
                        dst[i] = src[i] + ((i >= off) ? src[i - off] : 0);
                    __syncthreads();
                    int* t_ = src; src = dst; dst = t_;
                }
                for (int i = tid; i < ne; i += 256) dst[i] = i ? src[i-1] : 0;
                __syncthreads();
                for (int i = tid; i < M; i += 256){
                    int e = ent[i];
                    int pos = atomicAdd(&dst[e], 1);
                    out[pos] = make_int4(spans[i*2], e, i, 0);
                }
            } else {
                for (int i = tid; i < M; i += 256)
                    out[i] = make_int4(spans[i*2], ent[i], i, 0);
            }
            __syncthreads();
        }
    } else if (bid < off_e){
        int i = (bid - 1) * 256 + tid;
        if (i < gent_n) gent[i] = NEG_ENC;
    } else if (bid < off_w){
        int d = (bid - off_e) * 256 + tid;
        if (d < MAXD){
            float a0 = bs[0], a1 = bs[1];
            #pragma unroll 5
            for (int q = 0; q < 50; ++q){
                float w = Wemb[d*50 + q];
                a0 += w * Ws[(200+q)*2 + 0];
                a1 += w * Ws[(200+q)*2 + 1];
            }
            emb2[d*2 + 0] = a0;
            emb2[d*2 + 1] = a1;
        }
    } else if (bid < off_h){
        // Wt: 2*NPAD*512 elements, 4096 per block, stride-256 for coalescing
        const int base = (bid - off_w) * 4096;
        #pragma unroll
        for (int ii = 0; ii < 16; ++ii){
            int e = base + tid + 256*ii;
            if (e < 2*NPAD*H_DIM){
                int side = e / (NPAD*H_DIM);
                int rem  = e - side*(NPAD*H_DIM);
                int n    = rem / H_DIM;
                int k    = rem - n*H_DIM;
                const float* W = side ? Wd : Wc;
                Wt[e] = (n < NFEAT) ? f2bf(W[k*NFEAT + n]) : (unsigned short)0;
            }
        }
    } else {
        // h cast: 8 floats per thread
        const long base = (long)(bid - off_h) * 2048 + (long)tid * 8;
        if (base < (long)TT * H_DIM){
            float4 lo = *reinterpret_cast<const float4*>(h + base);
            float4 hi = *reinterpret_cast<const float4*>(h + base + 4);
            union { unsigned short us[8]; uint4 v; } o;
            o.us[0]=f2bf(lo.x); o.us[1]=f2bf(lo.y); o.us[2]=f2bf(lo.z); o.us[3]=f2bf(lo.w);
            o.us[4]=f2bf(hi.x); o.us[5]=f2bf(hi.y); o.us[6]=f2bf(hi.z); o.us[7]=f2bf(hi.w);
            *reinterpret_cast<uint4*>(hbf + base) = o.v;
        }
    }
}

// HW[side] = hbf @ W_side : [TT x 512] @ [512 x NPAD] -> f32 [TT x NPAD].
// One wave per 16-row M-tile per side; 7 n-tiles x 16 K-steps of
// mfma_f32_16x16x32_bf16. A/B frags loaded straight from global (L2-hot B).
__global__ __launch_bounds__(128) void hw_gemm(
    const unsigned short* __restrict__ hbf,
    const unsigned short* __restrict__ Wt,
    float* __restrict__ HW, int mt_total, int TT)
{
    const int wid  = blockIdx.x * 2 + (threadIdx.x >> 6);
    const int lane = threadIdx.x & 63;
    const int side = wid / mt_total;
    const int mt   = wid - side * mt_total;
    if (side > 1) return;

    const unsigned short* A = hbf + (size_t)(mt*16 + (lane & 15)) * H_DIM + (lane >> 4) * 8;
    const unsigned short* B = Wt + (size_t)side * NPAD * H_DIM
                                 + (size_t)(lane & 15) * H_DIM + (lane >> 4) * 8;
    float* D = HW + (size_t)side * TT * NPAD;

    f32x4 acc[NT];
    #pragma unroll
    for (int nt = 0; nt < NT; ++nt) acc[nt] = (f32x4){0.f,0.f,0.f,0.f};

    #pragma unroll 4
    for (int ks = 0; ks < H_DIM/32; ++ks){
        short8v a = *reinterpret_cast<const short8v*>(A + ks*32);
        #pragma unroll
        for (int nt = 0; nt < NT; ++nt){
            short8v b = *reinterpret_cast<const short8v*>(B + (size_t)nt*16*H_DIM + ks*32);
            acc[nt] = __builtin_amdgcn_mfma_f32_16x16x32_bf16(a, b, acc[nt], 0, 0, 0);
        }
    }

    const int col = lane & 15;
    const int r0  = (lane >> 4) * 4;
    #pragma unroll
    for (int nt = 0; nt < NT; ++nt){
        #pragma unroll
        for (int r = 0; r < 4; ++r)
            D[(size_t)(mt*16 + r0 + r) * NPAD + nt*16 + col] = acc[nt][r];
    }
}

// Per-mention: sum <=8 rows of HW, +b, tanh, fold Ws -> sc[m,2].
// One 128-thread block per mention (j = feature lane).
__global__ __launch_bounds__(128) void feat_kernel(
    const float* __restrict__ HW,
    const int* __restrict__ cspans, const int* __restrict__ dspans,
    const float* __restrict__ bc,   const float* __restrict__ bd,
    const float* __restrict__ Ws,
    float* __restrict__ sc_c, float* __restrict__ sc_d,
    int MCv, int MDv, int TT)
{
    __shared__ float red[2][2];
    const int bidx = blockIdx.x;
    const bool isd = (bidx >= MCv);
    const int  m   = isd ? (bidx - MCv) : bidx;
    const int* spans = isd ? dspans : cspans;
    const float* b   = isd ? bd : bc;
    const int  wsoff = isd ? NFEAT : 0;

    const int tid = threadIdx.x;
    const int s   = spans[m*2];
    const int len = spans[m*2 + 1] - s;   // 0..7

    float p0 = 0.f, p1 = 0.f;
    if (tid < NFEAT){
        const float* base = HW + (isd ? (size_t)TT*NPAD : 0) + (size_t)s*NPAD + tid;
        float v[8];
        #pragma unroll
        for (int r = 0; r < 8; ++r) v[r] = base[(size_t)r*NPAD];
        float val = 0.f;
        #pragma unroll
        for (int r = 0; r < 8; ++r) val += (r <= len) ? v[r] : 0.f;
        float f = tanhf(val + b[tid]);
        p0 = f * Ws[(wsoff + tid)*2 + 0];
        p1 = f * Ws[(wsoff + tid)*2 + 1];
    }
    #pragma unroll
    for (int k = 32; k >= 1; k >>= 1){
        p0 += __shfl_down(p0, k);
        p1 += __shfl_down(p1, k);
    }
    if ((tid & 63) == 0){ red[tid>>6][0] = p0; red[tid>>6][1] = p1; }
    __syncthreads();
    if (tid == 0){
        float* sc = isd ? sc_d : sc_c;
        sc[m*2 + 0] = red[0][0] + red[1][0];
        sc[m*2 + 1] = red[0][1] + red[1][1];
    }
}

// Segmented (by ce, contiguous after sort) suffix max-reduce + head atomics.
__device__ __forceinline__ void flush_run(
    float s0, float s1, int ce, int de, int nd, bool head,
    const bool okk[6], unsigned* __restrict__ gent)
{
    float a0 = s0, a1 = s1;
    #pragma unroll
    for (int k = 0; k < 6; ++k){
        float b0 = __shfl_down(a0, 1 << k);
        float b1 = __shfl_down(a1, 1 << k);
        if (okk[k]){ a0 = fmaxf(a0, b0); a1 = fmaxf(a1, b1); }
    }
    if (head && ce != INT_MAX){
        atomicMax(&gent[(ce*nd + de)*2 + 0], enc_f(a0));
        atomicMax(&gent[(ce*nd + de)*2 + 1], enc_f(a1));
    }
}

// 256 sorted chem mentions per block (one per lane); stream sorted dis
// mentions in staged chunks; per-lane running max per dis-entity run;
// boundary flush via wave-segmented reduce -> few global atomics.
__global__ __launch_bounds__(256) void pair_kernel(
    const int4* __restrict__ csorted, const int4* __restrict__ dsorted,
    const float* __restrict__ sc_c,   const float* __restrict__ sc_d,
    const float* __restrict__ emb2,   const int* __restrict__ ndp,
    unsigned* __restrict__ gent, int MCv, int MDv)
{
    __shared__ float2 s_e[MAXD];
    __shared__ int4   s_d[CHK];

    const int tid  = threadIdx.x;
    const int lane = tid & 63;
    const int nd   = *ndp;

    const float2* e2 = (const float2*)emb2;
    for (int i = tid; i < MAXD; i += 256) s_e[i] = e2[i];

    int   cs = 0, ce = INT_MAX;
    float c0 = 0.f, c1 = 0.f;
    {
        int ci = blockIdx.x * 256 + tid;
        if (ci < MCv){
            int4 r = csorted[ci];
            cs = r.x; ce = r.y;
            const float2 sc = *reinterpret_cast<const float2*>(&sc_c[2*r.z]);
            c0 = sc.x; c1 = sc.y;
        }
    }
    int ceprev = __shfl_up(ce, 1);
    const bool head = (lane == 0) || (ceprev != ce);
    bool okk[6];
    #pragma unroll
    for (int k = 0; k < 6; ++k) okk[k] = (__shfl_down(ce, 1 << k) == ce);

    for (int cb = blockIdx.y; cb * CHK < MDv; cb += DCH){
        const int dbase = cb * CHK;
        const int n = min(CHK, MDv - dbase);
        __syncthreads();   // protect s_d from previous chunk's readers
        for (int i = tid; i < n; i += 256){
            int4 r = dsorted[dbase + i];
            const float2 sd = *reinterpret_cast<const float2*>(&sc_d[2*r.z]);
            s_d[i] = make_int4(r.x, r.y, __float_as_int(sd.x), __float_as_int(sd.y));
        }
        __syncthreads();

        int   cur_de = s_d[0].y;
        float s0 = -INFINITY, s1 = -INFINITY;
        for (int j = 0; j < n; ++j){
            int4 dj = s_d[j];                 // broadcast b128
            if (dj.y != cur_de){              // uniform branch
                flush_run(s0, s1, ce, cur_de, nd, head, okk, gent);
                cur_de = dj.y; s0 = -INFINITY; s1 = -INFINITY;
            }
            int dd = cs - dj.x; dd = dd < 0 ? -dd : dd;
            dd = dd < (MAXD-1) ? dd : (MAXD-1);
            float2 e = s_e[dd];               // gather b64
            s0 = fmaxf(s0, c0 + __int_as_float(dj.z) + e.x);
            s1 = fmaxf(s1, c1 + __int_as_float(dj.w) + e.y);
        }
        flush_run(s0, s1, ce, cur_de, nd, head, okk, gent);
    }
}

__global__ void softmax_kernel(const unsigned* __restrict__ gent,
                               float* __restrict__ out, int npairs){
    int p = blockIdx.x * blockDim.x + threadIdx.x;
    if (p < npairs){
        float a = dec_f(gent[p*2 + 0]);
        float b = dec_f(gent[p*2 + 1]);
        float m = fmaxf(a, b);
        float ea = expf(a - m), eb = expf(b - m);
        float inv = 1.f / (ea + eb);
        out[p*2 + 0] = ea * inv;
        out[p*2 + 1] = eb * inv;
    }
}

extern "C" void kernel_launch(void* const* d_in, const int* in_sizes, int n_in,
                              void* d_out, int out_size, void* d_ws, size_t ws_size,
                              hipStream_t stream)
{
    const float* h      = (const float*)d_in[0];
    const int*   cspans = (const int*)  d_in[1];
    const int*   centp  = (const int*)  d_in[2];
    const int*   dspans = (const int*)  d_in[3];
    const int*   dentp  = (const int*)  d_in[4];
    const float* Wc     = (const float*)d_in[5];
    const float* bc     = (const float*)d_in[6];
    const float* Wd     = (const float*)d_in[7];
    const float* bd     = (const float*)d_in[8];
    const float* Wemb   = (const float*)d_in[9];
    const float* Ws     = (const float*)d_in[10];
    const float* bs     = (const float*)d_in[11];
    const int*   ncp    = (const int*)  d_in[12];
    const int*   ndp    = (const int*)  d_in[13];

    const int MCv    = in_sizes[1] / 2;
    const int MDv    = in_sizes[3] / 2;
    const int TT     = in_sizes[0] / H_DIM;
    const int npairs = out_size / 2;

    // ws layout (4B units): emb2[1280] | sc_c[2MC] | sc_d[2MD] | gent[out_size]
    //   | csorted[4MC] | dsorted[4MD] | hbf (ushort TT*512) | Wt (ushort 2*112*512)
    //   | HW (f32 2*TT*112)
    float*    wsf    = (float*)d_ws;
    float*    emb2   = wsf;
    float*    sc_c   = wsf + 1280;
    float*    sc_d   = sc_c + (size_t)MCv * 2;
    unsigned* gent   = (unsigned*)(sc_d + (size_t)MDv * 2);
    int4*     csorted= (int4*)(gent + out_size);
    int4*     dsorted= csorted + MCv;
    unsigned short* hbf = (unsigned short*)(dsorted + MDv);
    unsigned short* Wt  = hbf + (size_t)TT * H_DIM;
    float*    HW     = (float*)(Wt + 2 * NPAD * H_DIM);

    const int gb    = (out_size + 255) / 256;
    const int eb    = (MAXD + 255) / 256;
    const int wb    = (2*NPAD*H_DIM + 4095) / 4096;
    const int hb    = (int)(((long)TT * H_DIM + 2047) / 2048);
    const int off_e = 1 + gb;
    const int off_w = off_e + eb;
    const int off_h = off_w + wb;

    hipLaunchKernelGGL(prep_kernel, dim3(off_h + hb), dim3(256), 0, stream,
                       h, Wemb, Ws, bs, Wc, Wd, centp, dentp, ncp, ndp,
                       cspans, dspans, emb2, gent, out_size, Wt, hbf,
                       csorted, dsorted, MCv, MDv, TT, off_e, off_w, off_h);

    const int mt_total = TT / 16;
    hipLaunchKernelGGL(hw_gemm, dim3(mt_total), dim3(128), 0, stream,
                       hbf, Wt, HW, mt_total, TT);

    hipLaunchKernelGGL(feat_kernel, dim3(MCv + MDv), dim3(128), 0, stream,
                       HW, cspans, dspans, bc, bd, Ws, sc_c, sc_d, MCv, MDv, TT);

    hipLaunchKernelGGL(pair_kernel, dim3((MCv + 255)/256, DCH), dim3(256), 0, stream,
                       csorted, dsorted, sc_c, sc_d, emb2, ndp, gent, MCv, MDv);

    hipLaunchKernelGGL(softmax_kernel, dim3((npairs + 255)/256), dim3(256), 0, stream,
                       gent, (float*)d_out, npairs);
}

// Round 5
// 134.329 us; speedup vs baseline: 1.4357x; 1.1562x over previous
//
#include <hip/hip_runtime.h>
#include <math.h>
#include <limits.h>

// Fixed geometry from reference: T=8192, H=512, MC=MD=4096, N_ENT=128,
// MAX_DIST=600, feature dim 100 (padded to 112 for MFMA n-tiles).
#define H_DIM  512
#define NFEAT  100
#define NPAD   112
#define NT     7      // NPAD/16 n-tiles
#define MAXD   600
#define MAXE   2048   // sort fast-path entity-count limit
#define SB     16     // sort blocks per side (parallel counting sort)
#define CHK    64     // dis mentions per staged chunk in pair kernel
#define DCH    64     // grid.y = number of dis-chunk streams

#define NEG_ENC 0x007FFFFFu  // enc_f(-inf)

typedef __attribute__((ext_vector_type(8))) short short8v;  // 8 bf16
typedef __attribute__((ext_vector_type(4))) float f32x4;

// Monotonic float->uint mapping so unsigned atomicMax == float max.
__device__ __forceinline__ unsigned enc_f(float f){
    unsigned u = __float_as_uint(f);
    return (u & 0x80000000u) ? ~u : (u | 0x80000000u);
}
__device__ __forceinline__ float dec_f(unsigned e){
    unsigned u = (e & 0x80000000u) ? (e ^ 0x80000000u) : ~e;
    return __uint_as_float(u);
}
__device__ __forceinline__ unsigned short f2bf(float f){  // round-nearest-even
    unsigned x = __float_as_uint(f);
    return (unsigned short)((x + 0x7fffu + ((x >> 16) & 1u)) >> 16);
}

// Fused prep, block roles by blockIdx.x:
//  [0, 32)            : per-chunk entity histograms -> ghist (16 blocks/side)
//  [32, off_e)        : gent init to -inf
//  [off_e, off_w)     : emb2[d] = Wemb[d,:]@Ws[200:250] + bs
//  [off_w, off_h)     : Wt[side][n][k] = bf16(W_side[k][n])  (zero-pad n>=100)
//  [off_h, ...)       : hbf = bf16(h)
__global__ __launch_bounds__(256) void prep_kernel(
    const float* __restrict__ h,
    const float* __restrict__ Wemb, const float* __restrict__ Ws,
    const float* __restrict__ bs,
    const float* __restrict__ Wc,   const float* __restrict__ Wd,
    const int* __restrict__ cent, const int* __restrict__ dent,
    const int* __restrict__ ncp,  const int* __restrict__ ndp,
    float* __restrict__ emb2, unsigned* __restrict__ gent, int gent_n,
    unsigned short* __restrict__ Wt, unsigned short* __restrict__ hbf,
    int* __restrict__ ghist,
    int MCv, int MDv, int TT, int off_e, int off_w, int off_h)
{
    const int tid = threadIdx.x;
    const int bid = blockIdx.x;

    if (bid < 32){
        // counting phase of the parallel bucket sort
        __shared__ int hist[MAXE];
        const int side = bid >> 4;
        const int b    = bid & 15;
        const int ne   = side ? *ndp : *ncp;
        if (ne > MAXE) return;                 // fallback: no sort
        const int* ent = side ? dent : cent;
        const int  M   = side ? MDv : MCv;
        const int chunk = (M + SB - 1) / SB;
        const int i0 = b * chunk, i1 = min(M, i0 + chunk);
        for (int e = tid; e < ne; e += 256) hist[e] = 0;
        __syncthreads();
        for (int i = i0 + tid; i < i1; i += 256) atomicAdd(&hist[ent[i]], 1);
        __syncthreads();
        int* gh = ghist + (side*SB + b) * MAXE;
        for (int e = tid; e < ne; e += 256) gh[e] = hist[e];
    } else if (bid < off_e){
        int i = (bid - 32) * 256 + tid;
        if (i < gent_n) gent[i] = NEG_ENC;
    } else if (bid < off_w){
        int d = (bid - off_e) * 256 + tid;
        if (d < MAXD){
            float a0 = bs[0], a1 = bs[1];
            #pragma unroll 5
            for (int q = 0; q < 50; ++q){
                float w = Wemb[d*50 + q];
                a0 += w * Ws[(200+q)*2 + 0];
                a1 += w * Ws[(200+q)*2 + 1];
            }
            emb2[d*2 + 0] = a0;
            emb2[d*2 + 1] = a1;
        }
    } else if (bid < off_h){
        // Wt: 2*NPAD*512 elements, 4096 per block, stride-256 for coalescing
        const int base = (bid - off_w) * 4096;
        #pragma unroll
        for (int ii = 0; ii < 16; ++ii){
            int e = base + tid + 256*ii;
            if (e < 2*NPAD*H_DIM){
                int side = e / (NPAD*H_DIM);
                int rem  = e - side*(NPAD*H_DIM);
                int n    = rem / H_DIM;
                int k    = rem - n*H_DIM;
                const float* W = side ? Wd : Wc;
                Wt[e] = (n < NFEAT) ? f2bf(W[k*NFEAT + n]) : (unsigned short)0;
            }
        }
    } else {
        // h cast: 8 floats per thread
        const long base = (long)(bid - off_h) * 2048 + (long)tid * 8;
        if (base < (long)TT * H_DIM){
            float4 lo = *reinterpret_cast<const float4*>(h + base);
            float4 hi = *reinterpret_cast<const float4*>(h + base + 4);
            union { unsigned short us[8]; uint4 v; } o;
            o.us[0]=f2bf(lo.x); o.us[1]=f2bf(lo.y); o.us[2]=f2bf(lo.z); o.us[3]=f2bf(lo.w);
            o.us[4]=f2bf(hi.x); o.us[5]=f2bf(hi.y); o.us[6]=f2bf(hi.z); o.us[7]=f2bf(hi.w);
            *reinterpret_cast<uint4*>(hbf + base) = o.v;
        }
    }
}

// Blocks [0, mt_total): HW[side] = hbf @ W_side via mfma_f32_16x16x32_bf16,
// one wave per 16-row M-tile per side, 7 n-tiles x 16 K-steps.
// Blocks [mt_total, mt_total+32): scatter phase of the parallel counting sort
// (self-computes per-entity bases from ghist; no separate scan kernel).
__global__ __launch_bounds__(128) void hw_gemm(
    const unsigned short* __restrict__ hbf,
    const unsigned short* __restrict__ Wt,
    float* __restrict__ HW, int mt_total, int TT,
    const int* __restrict__ cent, const int* __restrict__ dent,
    const int* __restrict__ ncp,  const int* __restrict__ ndp,
    const int* __restrict__ cspans, const int* __restrict__ dspans,
    const int* __restrict__ ghist,
    int4* __restrict__ csorted, int4* __restrict__ dsorted,
    int MCv, int MDv)
{
    __shared__ int s_tot[MAXE];
    __shared__ int s_cur[MAXE];
    __shared__ int s_wsum[2];

    if ((int)blockIdx.x >= mt_total){
        // ---- scatter role ----
        const int sb   = blockIdx.x - mt_total;   // 0..31
        const int side = sb >> 4;
        const int b    = sb & 15;
        const int tid  = threadIdx.x;
        const int ne   = side ? *ndp : *ncp;
        const int* ent = side ? dent : cent;
        const int* spans = side ? dspans : cspans;
        int4* out      = side ? dsorted : csorted;
        const int M    = side ? MDv : MCv;
        const int chunk = (M + SB - 1) / SB;
        const int i0 = b * chunk, i1 = min(M, i0 + chunk);

        if (ne <= MAXE){
            const int* gh = ghist + side*SB*MAXE;
            for (int e = tid; e < ne; e += 128){
                int pre = 0, tot = 0;
                #pragma unroll
                for (int bb = 0; bb < SB; ++bb){
                    int v = gh[bb*MAXE + e];
                    tot += v;
                    pre += (bb < b) ? v : 0;
                }
                s_tot[e] = tot;
                s_cur[e] = pre;
            }
            __syncthreads();
            // exclusive scan of s_tot across ne, 128 threads
            const int per = (ne + 127) / 128;
            const int lo = min(tid*per, ne), hi = min(lo + per, ne);
            int sum = 0;
            for (int j = lo; j < hi; ++j) sum += s_tot[j];
            const int lane = tid & 63, w = tid >> 6;
            int x = sum;
            #pragma unroll
            for (int k = 1; k < 64; k <<= 1){
                int y = __shfl_up(x, k);
                if (lane >= k) x += y;
            }
            int excl = x - sum;
            if (lane == 63) s_wsum[w] = x;
            __syncthreads();
            if (w == 1) excl += s_wsum[0];
            int run = excl;
            for (int j = lo; j < hi; ++j){
                int t = s_tot[j];
                s_cur[j] += run;      // cursor = global base + cross-block pre
                run += t;
            }
            __syncthreads();
            for (int i = i0 + tid; i < i1; i += 128){
                int e = ent[i];
                int pos = atomicAdd(&s_cur[e], 1);
                out[pos] = make_int4(spans[i*2], e, i, 0);
            }
        } else {
            for (int i = i0 + tid; i < i1; i += 128)
                out[i] = make_int4(spans[i*2], ent[i], i, 0);
        }
        return;
    }

    // ---- GEMM role ----
    const int wid  = blockIdx.x * 2 + (threadIdx.x >> 6);
    const int lane = threadIdx.x & 63;
    const int side = wid / mt_total;
    const int mt   = wid - side * mt_total;
    if (side > 1) return;

    const unsigned short* A = hbf + (size_t)(mt*16 + (lane & 15)) * H_DIM + (lane >> 4) * 8;
    const unsigned short* B = Wt + (size_t)side * NPAD * H_DIM
                                 + (size_t)(lane & 15) * H_DIM + (lane >> 4) * 8;
    float* D = HW + (size_t)side * TT * NPAD;

    f32x4 acc[NT];
    #pragma unroll
    for (int nt = 0; nt < NT; ++nt) acc[nt] = (f32x4){0.f,0.f,0.f,0.f};

    #pragma unroll 4
    for (int ks = 0; ks < H_DIM/32; ++ks){
        short8v a = *reinterpret_cast<const short8v*>(A + ks*32);
        #pragma unroll
        for (int nt = 0; nt < NT; ++nt){
            short8v b = *reinterpret_cast<const short8v*>(B + (size_t)nt*16*H_DIM + ks*32);
            acc[nt] = __builtin_amdgcn_mfma_f32_16x16x32_bf16(a, b, acc[nt], 0, 0, 0);
        }
    }

    const int col = lane & 15;
    const int r0  = (lane >> 4) * 4;
    #pragma unroll
    for (int nt = 0; nt < NT; ++nt){
        #pragma unroll
        for (int r = 0; r < 4; ++r)
            D[(size_t)(mt*16 + r0 + r) * NPAD + nt*16 + col] = acc[nt][r];
    }
}

// Per-mention: sum <=8 rows of HW, +b, tanh, fold Ws -> sc[m,2].
// One 128-thread block per mention (j = feature lane).
__global__ __launch_bounds__(128) void feat_kernel(
    const float* __restrict__ HW,
    const int* __restrict__ cspans, const int* __restrict__ dspans,
    const float* __restrict__ bc,   const float* __restrict__ bd,
    const float* __restrict__ Ws,
    float* __restrict__ sc_c, float* __restrict__ sc_d,
    int MCv, int MDv, int TT)
{
    __shared__ float red[2][2];
    const int bidx = blockIdx.x;
    const bool isd = (bidx >= MCv);
    const int  m   = isd ? (bidx - MCv) : bidx;
    const int* spans = isd ? dspans : cspans;
    const float* b   = isd ? bd : bc;
    const int  wsoff = isd ? NFEAT : 0;

    const int tid = threadIdx.x;
    const int s   = spans[m*2];
    const int len = spans[m*2 + 1] - s;   // 0..7

    float p0 = 0.f, p1 = 0.f;
    if (tid < NFEAT){
        const float* base = HW + (isd ? (size_t)TT*NPAD : 0) + (size_t)s*NPAD + tid;
        float v[8];
        #pragma unroll
        for (int r = 0; r < 8; ++r) v[r] = base[(size_t)r*NPAD];
        float val = 0.f;
        #pragma unroll
        for (int r = 0; r < 8; ++r) val += (r <= len) ? v[r] : 0.f;
        float f = tanhf(val + b[tid]);
        p0 = f * Ws[(wsoff + tid)*2 + 0];
        p1 = f * Ws[(wsoff + tid)*2 + 1];
    }
    #pragma unroll
    for (int k = 32; k >= 1; k >>= 1){
        p0 += __shfl_down(p0, k);
        p1 += __shfl_down(p1, k);
    }
    if ((tid & 63) == 0){ red[tid>>6][0] = p0; red[tid>>6][1] = p1; }
    __syncthreads();
    if (tid == 0){
        float* sc = isd ? sc_d : sc_c;
        sc[m*2 + 0] = red[0][0] + red[1][0];
        sc[m*2 + 1] = red[0][1] + red[1][1];
    }
}

// Segmented (by ce, contiguous after sort) suffix max-reduce + head atomics.
__device__ __forceinline__ void flush_run(
    float s0, float s1, int ce, int de, int nd, bool head,
    const bool okk[6], unsigned* __restrict__ gent)
{
    float a0 = s0, a1 = s1;
    #pragma unroll
    for (int k = 0; k < 6; ++k){
        float b0 = __shfl_down(a0, 1 << k);
        float b1 = __shfl_down(a1, 1 << k);
        if (okk[k]){ a0 = fmaxf(a0, b0); a1 = fmaxf(a1, b1); }
    }
    if (head && ce != INT_MAX){
        atomicMax(&gent[(ce*nd + de)*2 + 0], enc_f(a0));
        atomicMax(&gent[(ce*nd + de)*2 + 1], enc_f(a1));
    }
}

// 256 sorted chem mentions per block (one per lane); stream sorted dis
// mentions in staged chunks; per-lane running max per dis-entity run;
// boundary flush via wave-segmented reduce -> few global atomics.
__global__ __launch_bounds__(256) void pair_kernel(
    const int4* __restrict__ csorted, const int4* __restrict__ dsorted,
    const float* __restrict__ sc_c,   const float* __restrict__ sc_d,
    const float* __restrict__ emb2,   const int* __restrict__ ndp,
    unsigned* __restrict__ gent, int MCv, int MDv)
{
    __shared__ float2 s_e[MAXD];
    __shared__ int4   s_d[CHK];

    const int tid  = threadIdx.x;
    const int lane = tid & 63;
    const int nd   = *ndp;

    const float2* e2 = (const float2*)emb2;
    for (int i = tid; i < MAXD; i += 256) s_e[i] = e2[i];

    int   cs = 0, ce = INT_MAX;
    float c0 = 0.f, c1 = 0.f;
    {
        int ci = blockIdx.x * 256 + tid;
        if (ci < MCv){
            int4 r = csorted[ci];
            cs = r.x; ce = r.y;
            const float2 sc = *reinterpret_cast<const float2*>(&sc_c[2*r.z]);
            c0 = sc.x; c1 = sc.y;
        }
    }
    int ceprev = __shfl_up(ce, 1);
    const bool head = (lane == 0) || (ceprev != ce);
    bool okk[6];
    #pragma unroll
    for (int k = 0; k < 6; ++k) okk[k] = (__shfl_down(ce, 1 << k) == ce);

    for (int cb = blockIdx.y; cb * CHK < MDv; cb += DCH){
        const int dbase = cb * CHK;
        const int n = min(CHK, MDv - dbase);
        __syncthreads();   // protect s_d from previous chunk's readers
        for (int i = tid; i < n; i += 256){
            int4 r = dsorted[dbase + i];
            const float2 sd = *reinterpret_cast<const float2*>(&sc_d[2*r.z]);
            s_d[i] = make_int4(r.x, r.y, __float_as_int(sd.x), __float_as_int(sd.y));
        }
        __syncthreads();

        int   cur_de = s_d[0].y;
        float s0 = -INFINITY, s1 = -INFINITY;
        for (int j = 0; j < n; ++j){
            int4 dj = s_d[j];                 // broadcast b128
            if (dj.y != cur_de){              // uniform branch
                flush_run(s0, s1, ce, cur_de, nd, head, okk, gent);
                cur_de = dj.y; s0 = -INFINITY; s1 = -INFINITY;
            }
            int dd = cs - dj.x; dd = dd < 0 ? -dd : dd;
            dd = dd < (MAXD-1) ? dd : (MAXD-1);
            float2 e = s_e[dd];               // gather b64
            s0 = fmaxf(s0, c0 + __int_as_float(dj.z) + e.x);
            s1 = fmaxf(s1, c1 + __int_as_float(dj.w) + e.y);
        }
        flush_run(s0, s1, ce, cur_de, nd, head, okk, gent);
    }
}

__global__ void softmax_kernel(const unsigned* __restrict__ gent,
                               float* __restrict__ out, int npairs){
    int p = blockIdx.x * blockDim.x + threadIdx.x;
    if (p < npairs){
        float a = dec_f(gent[p*2 + 0]);
        float b = dec_f(gent[p*2 + 1]);
        float m = fmaxf(a, b);
        float ea = expf(a - m), eb = expf(b - m);
        float inv = 1.f / (ea + eb);
        out[p*2 + 0] = ea * inv;
        out[p*2 + 1] = eb * inv;
    }
}

extern "C" void kernel_launch(void* const* d_in, const int* in_sizes, int n_in,
                              void* d_out, int out_size, void* d_ws, size_t ws_size,
                              hipStream_t stream)
{
    const float* h      = (const float*)d_in[0];
    const int*   cspans = (const int*)  d_in[1];
    const int*   centp  = (const int*)  d_in[2];
    const int*   dspans = (const int*)  d_in[3];
    const int*   dentp  = (const int*)  d_in[4];
    const float* Wc     = (const float*)d_in[5];
    const float* bc     = (const float*)d_in[6];
    const float* Wd     = (const float*)d_in[7];
    const float* bd     = (const float*)d_in[8];
    const float* Wemb   = (const float*)d_in[9];
    const float* Ws     = (const float*)d_in[10];
    const float* bs     = (const float*)d_in[11];
    const int*   ncp    = (const int*)  d_in[12];
    const int*   ndp    = (const int*)  d_in[13];

    const int MCv    = in_sizes[1] / 2;
    const int MDv    = in_sizes[3] / 2;
    const int TT     = in_sizes[0] / H_DIM;
    const int npairs = out_size / 2;

    // ws layout (4B units): emb2[1280] | sc_c[2MC] | sc_d[2MD] | gent[out_size]
    //   | csorted[4MC] | dsorted[4MD] | hbf (ushort TT*512) | Wt (ushort 2*112*512)
    //   | ghist (int 2*SB*MAXE) | HW (f32 2*TT*112)
    float*    wsf    = (float*)d_ws;
    float*    emb2   = wsf;
    float*    sc_c   = wsf + 1280;
    float*    sc_d   = sc_c + (size_t)MCv * 2;
    unsigned* gent   = (unsigned*)(sc_d + (size_t)MDv * 2);
    int4*     csorted= (int4*)(gent + out_size);
    int4*     dsorted= csorted + MCv;
    unsigned short* hbf = (unsigned short*)(dsorted + MDv);
    unsigned short* Wt  = hbf + (size_t)TT * H_DIM;
    int*      ghist  = (int*)(Wt + 2 * NPAD * H_DIM);
    float*    HW     = (float*)(ghist + 2 * SB * MAXE);

    const int gb    = (out_size + 255) / 256;
    const int eb    = (MAXD + 255) / 256;
    const int wb    = (2*NPAD*H_DIM + 4095) / 4096;
    const int hb    = (int)(((long)TT * H_DIM + 2047) / 2048);
    const int off_e = 32 + gb;
    const int off_w = off_e + eb;
    const int off_h = off_w + wb;

    hipLaunchKernelGGL(prep_kernel, dim3(off_h + hb), dim3(256), 0, stream,
                       h, Wemb, Ws, bs, Wc, Wd, centp, dentp, ncp, ndp,
                       emb2, gent, out_size, Wt, hbf, ghist,
                       MCv, MDv, TT, off_e, off_w, off_h);

    const int mt_total = TT / 16;
    hipLaunchKernelGGL(hw_gemm, dim3(mt_total + 32), dim3(128), 0, stream,
                       hbf, Wt, HW, mt_total, TT,
                       centp, dentp, ncp, ndp, cspans, dspans,
                       ghist, csorted, dsorted, MCv, MDv);

    hipLaunchKernelGGL(feat_kernel, dim3(MCv + MDv), dim3(128), 0, stream,
                       HW, cspans, dspans, bc, bd, Ws, sc_c, sc_d, MCv, MDv, TT);

    hipLaunchKernelGGL(pair_kernel, dim3((MCv + 255)/256, DCH), dim3(256), 0, stream,
                       csorted, dsorted, sc_c, sc_d, emb2, ndp, gent, MCv, MDv);

    hipLaunchKernelGGL(softmax_kernel, dim3((npairs + 255)/256), dim3(256), 0, stream,
                       gent, (float*)d_out, npairs);
}

// Round 6
// 131.685 us; speedup vs baseline: 1.4645x; 1.0201x over previous
//
#include <hip/hip_runtime.h>
#include <math.h>
#include <limits.h>

// Fixed geometry from reference: T=8192, H=512, MC=MD=4096, N_ENT=128,
// MAX_DIST=600, feature dim 100 (padded to 112 for MFMA n-tiles).
#define H_DIM  512
#define NFEAT  100
#define NPAD   112
#define NT     7      // NPAD/16 n-tiles
#define KW     4      // K-split waves in gemm_feat (each wave: 4 of 16 ks)
#define MAXD   600
#define MAXE   2048   // sort fast-path entity-count limit
#define SB     16     // sort blocks per side (parallel counting sort)
#define CHK    64     // dis mentions per staged chunk in pair kernel
#define DCH    64     // grid.y = number of dis-chunk streams

#define NEG_ENC 0x007FFFFFu  // enc_f(-inf)

typedef __attribute__((ext_vector_type(8))) short short8v;  // 8 bf16
typedef __attribute__((ext_vector_type(4))) float f32x4;

// Monotonic float->uint mapping so unsigned atomicMax == float max.
__device__ __forceinline__ unsigned enc_f(float f){
    unsigned u = __float_as_uint(f);
    return (u & 0x80000000u) ? ~u : (u | 0x80000000u);
}
__device__ __forceinline__ float dec_f(unsigned e){
    unsigned u = (e & 0x80000000u) ? (e ^ 0x80000000u) : ~e;
    return __uint_as_float(u);
}
__device__ __forceinline__ unsigned short f2bf(float f){  // round-nearest-even
    unsigned x = __float_as_uint(f);
    return (unsigned short)((x + 0x7fffu + ((x >> 16) & 1u)) >> 16);
}

// Fused prep, block roles by blockIdx.x:
//  [0, 32)            : per-chunk entity histograms -> ghist (16 blocks/side)
//  [32, off_e)        : gent init to -inf
//  [off_e, off_w)     : emb2[d] = Wemb[d,:]@Ws[200:250] + bs
//  [off_w, off_h)     : Wt[side][n][k] = bf16(W_side[k][n])  (zero-pad n>=100)
//  [off_h, ...)       : S[row] = bf16(span-sum of h rows)  (4 rows/block)
__global__ __launch_bounds__(256) void prep_kernel(
    const float* __restrict__ h,
    const float* __restrict__ Wemb, const float* __restrict__ Ws,
    const float* __restrict__ bs,
    const float* __restrict__ Wc,   const float* __restrict__ Wd,
    const int* __restrict__ cent, const int* __restrict__ dent,
    const int* __restrict__ ncp,  const int* __restrict__ ndp,
    const int* __restrict__ cspans, const int* __restrict__ dspans,
    float* __restrict__ emb2, unsigned* __restrict__ gent, int gent_n,
    unsigned short* __restrict__ Wt, unsigned short* __restrict__ S,
    int* __restrict__ ghist,
    int MCv, int MDv, int MCs16, int Rtot, int off_e, int off_w, int off_h)
{
    const int tid = threadIdx.x;
    const int bid = blockIdx.x;

    if (bid < 32){
        __shared__ int hist[MAXE];
        const int side = bid >> 4;
        const int b    = bid & 15;
        const int ne   = side ? *ndp : *ncp;
        if (ne > MAXE) return;                 // fallback: no sort
        const int* ent = side ? dent : cent;
        const int  M   = side ? MDv : MCv;
        const int chunk = (M + SB - 1) / SB;
        const int i0 = b * chunk, i1 = min(M, i0 + chunk);
        for (int e = tid; e < ne; e += 256) hist[e] = 0;
        __syncthreads();
        for (int i = i0 + tid; i < i1; i += 256) atomicAdd(&hist[ent[i]], 1);
        __syncthreads();
        int* gh = ghist + (side*SB + b) * MAXE;
        for (int e = tid; e < ne; e += 256) gh[e] = hist[e];
    } else if (bid < off_e){
        int i = (bid - 32) * 256 + tid;
        if (i < gent_n) gent[i] = NEG_ENC;
    } else if (bid < off_w){
        int d = (bid - off_e) * 256 + tid;
        if (d < MAXD){
            float a0 = bs[0], a1 = bs[1];
            #pragma unroll 5
            for (int q = 0; q < 50; ++q){
                float w = Wemb[d*50 + q];
                a0 += w * Ws[(200+q)*2 + 0];
                a1 += w * Ws[(200+q)*2 + 1];
            }
            emb2[d*2 + 0] = a0;
            emb2[d*2 + 1] = a1;
        }
    } else if (bid < off_h){
        const int base = (bid - off_w) * 4096;
        #pragma unroll
        for (int ii = 0; ii < 16; ++ii){
            int e = base + tid + 256*ii;
            if (e < 2*NPAD*H_DIM){
                int side = e / (NPAD*H_DIM);
                int rem  = e - side*(NPAD*H_DIM);
                int n    = rem / H_DIM;
                int k    = rem - n*H_DIM;
                const float* W = side ? Wd : Wc;
                Wt[e] = (n < NFEAT) ? f2bf(W[k*NFEAT + n]) : (unsigned short)0;
            }
        }
    } else {
        // span-sum role: 4 rows per block, 64 threads (8 cols) per row.
        const int row = (bid - off_h) * 4 + (tid >> 6);
        if (row < Rtot){
            const int side = (row >= MCs16);
            const int ml   = side ? (row - MCs16) : row;
            const int M    = side ? MDv : MCv;
            const int col0 = (tid & 63) * 8;
            float a0=0.f,a1=0.f,a2=0.f,a3=0.f,a4=0.f,a5=0.f,a6=0.f,a7=0.f;
            if (ml < M){
                const int* spans = side ? dspans : cspans;
                const int s   = spans[ml*2];
                const int len = spans[ml*2 + 1] - s;   // 0..7
                const float* hp = h + (size_t)s * H_DIM + col0;
                float4 v0[8], v1[8];
                #pragma unroll
                for (int r = 0; r < 8; ++r){
                    v0[r] = *reinterpret_cast<const float4*>(hp + (size_t)r*H_DIM);
                    v1[r] = *reinterpret_cast<const float4*>(hp + (size_t)r*H_DIM + 4);
                }
                #pragma unroll
                for (int r = 0; r < 8; ++r){
                    if (r <= len){
                        a0+=v0[r].x; a1+=v0[r].y; a2+=v0[r].z; a3+=v0[r].w;
                        a4+=v1[r].x; a5+=v1[r].y; a6+=v1[r].z; a7+=v1[r].w;
                    }
                }
            }
            union { unsigned short us[8]; uint4 v; } o;
            o.us[0]=f2bf(a0); o.us[1]=f2bf(a1); o.us[2]=f2bf(a2); o.us[3]=f2bf(a3);
            o.us[4]=f2bf(a4); o.us[5]=f2bf(a5); o.us[6]=f2bf(a6); o.us[7]=f2bf(a7);
            *reinterpret_cast<uint4*>(S + (size_t)row * H_DIM + col0) = o.v;
        }
    }
}

// Blocks [0, mtc+mtd): sc = rowreduce(tanh(S@W + b) * Ws) via MFMA with
// 4-way K-split (4 waves/block, partials combined in LDS; wave 0 epilogue).
// Blocks [mtc+mtd, +32): scatter phase of the parallel counting sort.
__global__ __launch_bounds__(256) void gemm_feat(
    const unsigned short* __restrict__ S,
    const unsigned short* __restrict__ Wt,
    const float* __restrict__ bc, const float* __restrict__ bd,
    const float* __restrict__ Ws,
    float* __restrict__ sc_c, float* __restrict__ sc_d,
    const int* __restrict__ cent, const int* __restrict__ dent,
    const int* __restrict__ ncp,  const int* __restrict__ ndp,
    const int* __restrict__ cspans, const int* __restrict__ dspans,
    const int* __restrict__ ghist,
    int4* __restrict__ csorted, int4* __restrict__ dsorted,
    int mtc, int mtd, int MCv, int MDv, int MCs16)
{
    __shared__ float s_acc[KW-1][NT*4][64];
    __shared__ int   s_tot[MAXE];
    __shared__ int   s_cur[MAXE];
    __shared__ int   s_wsum[4];

    const int tid  = threadIdx.x;
    const int lane = tid & 63;
    const int w    = tid >> 6;
    const int bid  = blockIdx.x;

    if (bid >= mtc + mtd){
        // ---- scatter role ----
        const int sb   = bid - (mtc + mtd);   // 0..31
        const int side = sb >> 4;
        const int b    = sb & 15;
        const int ne   = side ? *ndp : *ncp;
        const int* ent = side ? dent : cent;
        const int* spans = side ? dspans : cspans;
        int4* out      = side ? dsorted : csorted;
        const int M    = side ? MDv : MCv;
        const int chunk = (M + SB - 1) / SB;
        const int i0 = b * chunk, i1 = min(M, i0 + chunk);

        if (ne <= MAXE){
            const int* gh = ghist + side*SB*MAXE;
            for (int e = tid; e < ne; e += 256){
                int pre = 0, tot = 0;
                #pragma unroll
                for (int bb = 0; bb < SB; ++bb){
                    int v = gh[bb*MAXE + e];
                    tot += v;
                    pre += (bb < b) ? v : 0;
                }
                s_tot[e] = tot;
                s_cur[e] = pre;
            }
            __syncthreads();
            const int per = (ne + 255) / 256;
            const int lo = min(tid*per, ne), hi = min(lo + per, ne);
            int sum = 0;
            for (int j = lo; j < hi; ++j) sum += s_tot[j];
            int x = sum;
            #pragma unroll
            for (int k = 1; k < 64; k <<= 1){
                int y = __shfl_up(x, k);
                if (lane >= k) x += y;
            }
            int excl = x - sum;
            if (lane == 63) s_wsum[w] = x;
            __syncthreads();
            for (int ww = 0; ww < w; ++ww) excl += s_wsum[ww];
            int run = excl;
            for (int j = lo; j < hi; ++j){
                s_cur[j] += run;
                run += s_tot[j];
            }
            __syncthreads();
            for (int i = i0 + tid; i < i1; i += 256){
                int e = ent[i];
                int pos = atomicAdd(&s_cur[e], 1);
                out[pos] = make_int4(spans[i*2], e, i, 0);
            }
        } else {
            for (int i = i0 + tid; i < i1; i += 256)
                out[i] = make_int4(spans[i*2], ent[i], i, 0);
        }
        return;
    }

    // ---- GEMM + fused feature epilogue ----
    const int side = (bid >= mtc);
    const int mt   = side ? (bid - mtc) : bid;
    const int row0 = (side ? MCs16 : 0) + mt*16;

    const unsigned short* A = S + (size_t)(row0 + (lane & 15)) * H_DIM
                                + (lane >> 4) * 8 + w * 4 * 32;
    const unsigned short* B = Wt + (size_t)side * NPAD * H_DIM
                                 + (size_t)(lane & 15) * H_DIM
                                 + (lane >> 4) * 8 + w * 4 * 32;

    f32x4 acc[NT];
    #pragma unroll
    for (int nt = 0; nt < NT; ++nt) acc[nt] = (f32x4){0.f,0.f,0.f,0.f};

    #pragma unroll
    for (int ks = 0; ks < 4; ++ks){
        short8v a = *reinterpret_cast<const short8v*>(A + ks*32);
        #pragma unroll
        for (int nt = 0; nt < NT; ++nt){
            short8v b = *reinterpret_cast<const short8v*>(B + (size_t)nt*16*H_DIM + ks*32);
            acc[nt] = __builtin_amdgcn_mfma_f32_16x16x32_bf16(a, b, acc[nt], 0, 0, 0);
        }
    }

    if (w > 0){
        #pragma unroll
        for (int nt = 0; nt < NT; ++nt)
            #pragma unroll
            for (int r = 0; r < 4; ++r)
                s_acc[w-1][nt*4 + r][lane] = acc[nt][r];
    }
    __syncthreads();
    if (w == 0){
        #pragma unroll
        for (int nt = 0; nt < NT; ++nt)
            #pragma unroll
            for (int r = 0; r < 4; ++r)
                acc[nt][r] += s_acc[0][nt*4+r][lane]
                            + s_acc[1][nt*4+r][lane]
                            + s_acc[2][nt*4+r][lane];

        const float* bvec = side ? bd : bc;
        const int    wsoff = side ? NFEAT : 0;
        const int    nb    = lane & 15;
        float bb[NT], w0[NT], w1[NT];
        #pragma unroll
        for (int nt = 0; nt < NT; ++nt){
            int n = nt*16 + nb;
            bool v = (n < NFEAT);
            bb[nt] = v ? bvec[n] : 0.f;
            w0[nt] = v ? Ws[(wsoff + n)*2 + 0] : 0.f;
            w1[nt] = v ? Ws[(wsoff + n)*2 + 1] : 0.f;
        }
        const int ml0 = mt*16 + (lane >> 4)*4;
        const int M   = side ? MDv : MCv;
        float* sc     = side ? sc_d : sc_c;
        #pragma unroll
        for (int r = 0; r < 4; ++r){
            float p0 = 0.f, p1 = 0.f;
            #pragma unroll
            for (int nt = 0; nt < NT; ++nt){
                float f = tanhf(acc[nt][r] + bb[nt]);
                p0 += f * w0[nt];
                p1 += f * w1[nt];
            }
            #pragma unroll
            for (int k = 1; k < 16; k <<= 1){
                p0 += __shfl_xor(p0, k);
                p1 += __shfl_xor(p1, k);
            }
            int ml = ml0 + r;
            if (nb == 0 && ml < M){
                sc[ml*2 + 0] = p0;
                sc[ml*2 + 1] = p1;
            }
        }
    }
}

// Segmented (by ce, contiguous after sort) suffix max-reduce + head atomics.
__device__ __forceinline__ void flush_run(
    float s0, float s1, int ce, int de, int nd, bool head,
    const bool okk[6], unsigned* __restrict__ gent)
{
    float a0 = s0, a1 = s1;
    #pragma unroll
    for (int k = 0; k < 6; ++k){
        float b0 = __shfl_down(a0, 1 << k);
        float b1 = __shfl_down(a1, 1 << k);
        if (okk[k]){ a0 = fmaxf(a0, b0); a1 = fmaxf(a1, b1); }
    }
    if (head && ce != INT_MAX){
        atomicMax(&gent[(ce*nd + de)*2 + 0], enc_f(a0));
        atomicMax(&gent[(ce*nd + de)*2 + 1], enc_f(a1));
    }
}

// 256 sorted chem mentions per block (one per lane); stream sorted dis
// mentions in staged chunks; per-lane running max per dis-entity run;
// boundary flush via wave-segmented reduce -> few global atomics.
__global__ __launch_bounds__(256) void pair_kernel(
    const int4* __restrict__ csorted, const int4* __restrict__ dsorted,
    const float* __restrict__ sc_c,   const float* __restrict__ sc_d,
    const float* __restrict__ emb2,   const int* __restrict__ ndp,
    unsigned* __restrict__ gent, int MCv, int MDv)
{
    __shared__ float2 s_e[MAXD];
    __shared__ int4   s_d[CHK];

    const int tid  = threadIdx.x;
    const int lane = tid & 63;
    const int nd   = *ndp;

    const float2* e2 = (const float2*)emb2;
    for (int i = tid; i < MAXD; i += 256) s_e[i] = e2[i];

    int   cs = 0, ce = INT_MAX;
    float c0 = 0.f, c1 = 0.f;
    {
        int ci = blockIdx.x * 256 + tid;
        if (ci < MCv){
            int4 r = csorted[ci];
            cs = r.x; ce = r.y;
            const float2 sc = *reinterpret_cast<const float2*>(&sc_c[2*r.z]);
            c0 = sc.x; c1 = sc.y;
        }
    }
    int ceprev = __shfl_up(ce, 1);
    const bool head = (lane == 0) || (ceprev != ce);
    bool okk[6];
    #pragma unroll
    for (int k = 0; k < 6; ++k) okk[k] = (__shfl_down(ce, 1 << k) == ce);

    for (int cb = blockIdx.y; cb * CHK < MDv; cb += DCH){
        const int dbase = cb * CHK;
        const int n = min(CHK, MDv - dbase);
        __syncthreads();   // protect s_d from previous chunk's readers
        for (int i = tid; i < n; i += 256){
            int4 r = dsorted[dbase + i];
            const float2 sd = *reinterpret_cast<const float2*>(&sc_d[2*r.z]);
            s_d[i] = make_int4(r.x, r.y, __float_as_int(sd.x), __float_as_int(sd.y));
        }
        __syncthreads();

        int   cur_de = s_d[0].y;
        float s0 = -INFINITY, s1 = -INFINITY;
        for (int j = 0; j < n; ++j){
            int4 dj = s_d[j];                 // broadcast b128
            if (dj.y != cur_de){              // uniform branch
                flush_run(s0, s1, ce, cur_de, nd, head, okk, gent);
                cur_de = dj.y; s0 = -INFINITY; s1 = -INFINITY;
            }
            int dd = cs - dj.x; dd = dd < 0 ? -dd : dd;
            dd = dd < (MAXD-1) ? dd : (MAXD-1);
            float2 e = s_e[dd];               // gather b64
            s0 = fmaxf(s0, c0 + __int_as_float(dj.z) + e.x);
            s1 = fmaxf(s1, c1 + __int_as_float(dj.w) + e.y);
        }
        flush_run(s0, s1, ce, cur_de, nd, head, okk, gent);
    }
}

__global__ void softmax_kernel(const unsigned* __restrict__ gent,
                               float* __restrict__ out, int npairs){
    int p = blockIdx.x * blockDim.x + threadIdx.x;
    if (p < npairs){
        float a = dec_f(gent[p*2 + 0]);
        float b = dec_f(gent[p*2 + 1]);
        float m = fmaxf(a, b);
        float ea = expf(a - m), eb = expf(b - m);
        float inv = 1.f / (ea + eb);
        out[p*2 + 0] = ea * inv;
        out[p*2 + 1] = eb * inv;
    }
}

extern "C" void kernel_launch(void* const* d_in, const int* in_sizes, int n_in,
                              void* d_out, int out_size, void* d_ws, size_t ws_size,
                              hipStream_t stream)
{
    const float* h      = (const float*)d_in[0];
    const int*   cspans = (const int*)  d_in[1];
    const int*   centp  = (const int*)  d_in[2];
    const int*   dspans = (const int*)  d_in[3];
    const int*   dentp  = (const int*)  d_in[4];
    const float* Wc     = (const float*)d_in[5];
    const float* bc     = (const float*)d_in[6];
    const float* Wd     = (const float*)d_in[7];
    const float* bd     = (const float*)d_in[8];
    const float* Wemb   = (const float*)d_in[9];
    const float* Ws     = (const float*)d_in[10];
    const float* bs     = (const float*)d_in[11];
    const int*   ncp    = (const int*)  d_in[12];
    const int*   ndp    = (const int*)  d_in[13];

    const int MCv    = in_sizes[1] / 2;
    const int MDv    = in_sizes[3] / 2;
    const int npairs = out_size / 2;

    const int mtc   = (MCv + 15) / 16;
    const int mtd   = (MDv + 15) / 16;
    const int MCs16 = mtc * 16;
    const int Rtot  = (mtc + mtd) * 16;

    // ws layout (4B units): emb2[1280] | sc_c[2MC] | sc_d[2MD] | gent[out_size]
    //   | csorted[4MC] | dsorted[4MD] | S (ushort Rtot*512) | Wt (ushort 2*112*512)
    //   | ghist (int 2*SB*MAXE)
    float*    wsf    = (float*)d_ws;
    float*    emb2   = wsf;
    float*    sc_c   = wsf + 1280;
    float*    sc_d   = sc_c + (size_t)MCv * 2;
    unsigned* gent   = (unsigned*)(sc_d + (size_t)MDv * 2);
    int4*     csorted= (int4*)(gent + out_size);
    int4*     dsorted= csorted + MCv;
    unsigned short* S  = (unsigned short*)(dsorted + MDv);
    unsigned short* Wt = S + (size_t)Rtot * H_DIM;
    int*      ghist  = (int*)(Wt + 2 * NPAD * H_DIM);

    const int gb    = (out_size + 255) / 256;
    const int eb    = (MAXD + 255) / 256;
    const int wb    = (2*NPAD*H_DIM + 4095) / 4096;
    const int sb    = (Rtot + 3) / 4;
    const int off_e = 32 + gb;
    const int off_w = off_e + eb;
    const int off_h = off_w + wb;

    hipLaunchKernelGGL(prep_kernel, dim3(off_h + sb), dim3(256), 0, stream,
                       h, Wemb, Ws, bs, Wc, Wd, centp, dentp, ncp, ndp,
                       cspans, dspans, emb2, gent, out_size, Wt, S, ghist,
                       MCv, MDv, MCs16, Rtot, off_e, off_w, off_h);

    hipLaunchKernelGGL(gemm_feat, dim3(mtc + mtd + 32), dim3(256), 0, stream,
                       S, Wt, bc, bd, Ws, sc_c, sc_d,
                       centp, dentp, ncp, ndp, cspans, dspans,
                       ghist, csorted, dsorted, mtc, mtd, MCv, MDv, MCs16);

    hipLaunchKernelGGL(pair_kernel, dim3((MCv + 255)/256, DCH), dim3(256), 0, stream,
                       csorted, dsorted, sc_c, sc_d, emb2, ndp, gent, MCv, MDv);

    hipLaunchKernelGGL(softmax_kernel, dim3((npairs + 255)/256), dim3(256), 0, stream,
                       gent, (float*)d_out, npairs);
}